// Round 1
// baseline (1246.073 us; speedup 1.0000x reference)
//
#include <hip/hip_runtime.h>
#include <math.h>

// Problem constants (fixed by setup_inputs)
#define Bb 8
#define Cc 192
#define NHEADS 8
#define HDim 24
#define Him 128
#define Wim 128
#define Ntok 16384   // H*W
#define EPSBN 1e-5f

// Workspace map (floats):
//   qbuf  [B*C*N]   (reused as convx after k_gram)
//   kbuf  [B*C*N]
//   vbuf  [B*C*N]
//   gram  [B*8*576] (atomically accumulated -> memset 0 each launch)
//   ssq_q [B*C], ssq_k [B*C] (atomic)
//   vmean [B*C]
//   attn  [B*8*576] (softmaxed)
//   sig_ch[B*C], sig_sp[B*N]
// total = 75,708,416 floats = 302,833,664 bytes

static __device__ __forceinline__ float gelu_f(float v) {
    return 0.5f * v * (1.0f + erff(v * 0.70710678118654752f));
}
static __device__ __forceinline__ float sigmoid_f(float v) {
    return 1.0f / (1.0f + expf(-v));
}

// ---------------------------------------------------------------------------
// K1: qkv projection. grid (N/64, B, 3sections). Each block: 64 tokens x 192
// cols of section sec (0=q,1=k,2=v). Output transposed to (B, C, N) per buffer.
// A-tile in LDS (stride 193: kills the (192%32==0) bank aliasing), B operand as
// float4 from global (442 KB total, L2-resident broadcast). 4x12 reg blocking.
// ---------------------------------------------------------------------------
__global__ __launch_bounds__(256) void k_qkv(const float* __restrict__ x,
                                             const float* __restrict__ w,
                                             float* __restrict__ qkv)
{
    __shared__ float xs[64 * 193];
    const int t = threadIdx.x;
    const int n0 = blockIdx.x * 64;
    const int b = blockIdx.y;
    const int sec = blockIdx.z;
    const float* xp = x + ((size_t)b * Ntok + n0) * Cc;
    for (int e = t; e < 64 * 192; e += 256) {
        int r = e / 192, kk = e - r * 192;
        xs[r * 193 + kk] = xp[e];
    }
    __syncthreads();
    const int tx = t & 15, ty = t >> 4;
    const int r0 = ty * 4, c0 = tx * 12;
    float acc[4][12];
#pragma unroll
    for (int i = 0; i < 4; ++i)
#pragma unroll
        for (int j = 0; j < 12; ++j) acc[i][j] = 0.f;
    const float* wbase = w + sec * 192 + c0;
    for (int kk = 0; kk < 192; ++kk) {
        float a0 = xs[(r0 + 0) * 193 + kk];
        float a1 = xs[(r0 + 1) * 193 + kk];
        float a2 = xs[(r0 + 2) * 193 + kk];
        float a3 = xs[(r0 + 3) * 193 + kk];
        const float4* wp = (const float4*)(wbase + (size_t)kk * 576);
        float4 b0 = wp[0], b1 = wp[1], b2 = wp[2];
        float bb[12] = {b0.x, b0.y, b0.z, b0.w, b1.x, b1.y, b1.z, b1.w,
                        b2.x, b2.y, b2.z, b2.w};
#pragma unroll
        for (int j = 0; j < 12; ++j) {
            acc[0][j] = fmaf(a0, bb[j], acc[0][j]);
            acc[1][j] = fmaf(a1, bb[j], acc[1][j]);
            acc[2][j] = fmaf(a2, bb[j], acc[2][j]);
            acc[3][j] = fmaf(a3, bb[j], acc[3][j]);
        }
    }
    __syncthreads();   // reuse xs as transpose-staging for coalesced store
#pragma unroll
    for (int i = 0; i < 4; ++i)
#pragma unroll
        for (int j = 0; j < 12; ++j)
            xs[(r0 + i) * 193 + (c0 + j)] = acc[i][j];
    __syncthreads();
    float* ob = qkv + (size_t)sec * Bb * Cc * Ntok + (size_t)b * Cc * Ntok + n0;
    for (int e = t; e < 64 * 192; e += 256) {
        int ch = e >> 6, n = e & 63;   // n fastest -> 256B contiguous per wave
        ob[(size_t)ch * Ntok + n] = xs[n * 193 + ch];
    }
}

// ---------------------------------------------------------------------------
// K2: Gram matrices + sum-of-squares. grid (N/256, HEADS, B). Stages 24x256
// q,k slabs (stride 257 pad), each thread owns 2-3 of the 576 (c,d) entries,
// atomicAdd partials. Norms applied later (post-hoc normalization is exact
// because L2-normalize is a per-row scalar).
// ---------------------------------------------------------------------------
__global__ __launch_bounds__(256) void k_gram(const float* __restrict__ qbuf,
                                              const float* __restrict__ kbuf,
                                              float* __restrict__ gram,
                                              float* __restrict__ ssq_q,
                                              float* __restrict__ ssq_k)
{
    __shared__ float qc[24 * 257];
    __shared__ float kc[24 * 257];
    const int t = threadIdx.x;
    const int n0 = blockIdx.x * 256;
    const int h = blockIdx.y;
    const int b = blockIdx.z;
    const float* qb = qbuf + ((size_t)b * Cc + h * HDim) * Ntok + n0;
    const float* kb = kbuf + ((size_t)b * Cc + h * HDim) * Ntok + n0;
    for (int e = t; e < 24 * 256; e += 256) {
        int c = e >> 8, n = e & 255;
        qc[c * 257 + n] = qb[(size_t)c * Ntok + n];
        kc[c * 257 + n] = kb[(size_t)c * Ntok + n];
    }
    __syncthreads();
    float g0 = 0.f, g1 = 0.f, g2 = 0.f;
    const int c1 = t / 24, d1 = t % 24;
    const int e2 = t + 256; const int c2 = e2 / 24, d2 = e2 % 24;
    const int e3 = t + 512;
    const int c3 = (t < 64) ? e3 / 24 : 0, d3 = (t < 64) ? e3 % 24 : 0;
    for (int n = 0; n < 256; ++n) {
        g0 = fmaf(qc[c1 * 257 + n], kc[d1 * 257 + n], g0);
        g1 = fmaf(qc[c2 * 257 + n], kc[d2 * 257 + n], g1);
        g2 = fmaf(qc[c3 * 257 + n], kc[d3 * 257 + n], g2);
    }
    float* gp = gram + (size_t)(b * NHEADS + h) * 576;
    atomicAdd(gp + t, g0);
    atomicAdd(gp + e2, g1);
    if (t < 64) atomicAdd(gp + e3, g2);
    if (t < 24) {
        float s = 0.f;
        for (int n = 0; n < 256; ++n) { float v = qc[t * 257 + n]; s = fmaf(v, v, s); }
        atomicAdd(ssq_q + b * Cc + h * HDim + t, s);
    } else if (t < 48) {
        int d = t - 24; float s = 0.f;
        for (int n = 0; n < 256; ++n) { float v = kc[d * 257 + n]; s = fmaf(v, v, s); }
        atomicAdd(ssq_k + b * Cc + h * HDim + d, s);
    }
}

// K3: per-channel mean of v (for the SE pool closed form). grid (C, B).
__global__ __launch_bounds__(256) void k_vmean(const float* __restrict__ vbuf,
                                               float* __restrict__ vmean)
{
    __shared__ float red[256];
    const int ch = blockIdx.x, b = blockIdx.y, t = threadIdx.x;
    const float* vp = vbuf + ((size_t)b * Cc + ch) * Ntok;
    float s = 0.f;
    for (int n = t; n < Ntok; n += 256) s += vp[n];
    red[t] = s; __syncthreads();
    for (int k = 128; k > 0; k >>= 1) { if (t < k) red[t] += red[t + k]; __syncthreads(); }
    if (t == 0) vmean[b * Cc + ch] = red[0] * (1.f / (float)Ntok);
}

// K4: normalize gram -> softmax attn; pooled = attn @ vmean; channel-gate MLP.
// grid (B). Tiny.
__global__ __launch_bounds__(256) void k_attn(const float* __restrict__ gram,
                                              const float* __restrict__ ssq_q,
                                              const float* __restrict__ ssq_k,
                                              const float* __restrict__ temperature,
                                              const float* __restrict__ vmean,
                                              const float* __restrict__ ci_w1,
                                              const float* __restrict__ ci_b1,
                                              const float* __restrict__ bn2_g,
                                              const float* __restrict__ bn2_b,
                                              const float* __restrict__ bn2_m,
                                              const float* __restrict__ bn2_v,
                                              const float* __restrict__ ci_w2,
                                              const float* __restrict__ ci_b2,
                                              float* __restrict__ attn,
                                              float* __restrict__ sig_ch)
{
    __shared__ float pooled[192];
    __shared__ float cmv[24];
    const int b = blockIdx.x, t = threadIdx.x;
    if (t < 192) {
        int h = t / 24, c = t % 24;
        const float* gp = gram + (size_t)(b * NHEADS + h) * 576 + c * 24;
        float qn = fmaxf(sqrtf(ssq_q[b * Cc + h * HDim + c]), 1e-12f);
        float temp = temperature[h];
        float logit[24];
        float m = -1e30f;
#pragma unroll
        for (int d = 0; d < 24; ++d) {
            float kn = fmaxf(sqrtf(ssq_k[b * Cc + h * HDim + d]), 1e-12f);
            float l = gp[d] / (qn * kn) * temp;
            logit[d] = l; m = fmaxf(m, l);
        }
        float s = 0.f;
#pragma unroll
        for (int d = 0; d < 24; ++d) { float e = expf(logit[d] - m); logit[d] = e; s += e; }
        float inv = 1.f / s;
        float pool = 0.f;
        float* ap = attn + (size_t)(b * NHEADS + h) * 576 + c * 24;
#pragma unroll
        for (int d = 0; d < 24; ++d) {
            float a = logit[d] * inv;
            ap[d] = a;
            pool = fmaf(a, vmean[b * Cc + h * HDim + d], pool);
        }
        pooled[h * 24 + c] = pool;
    }
    __syncthreads();
    if (t < 24) {
        float z = ci_b1[t];
        for (int c = 0; c < 192; ++c) z = fmaf(ci_w1[t * 192 + c], pooled[c], z);
        float sc = bn2_g[t] / sqrtf(bn2_v[t] + EPSBN);
        z = z * sc + (bn2_b[t] - bn2_m[t] * sc);
        cmv[t] = gelu_f(z);
    }
    __syncthreads();
    if (t < 192) {
        float z = ci_b2[t];
#pragma unroll
        for (int o = 0; o < 24; ++o) z = fmaf(ci_w2[t * 24 + o], cmv[o], z);
        sig_ch[b * Cc + t] = sigmoid_f(z);
    }
}

// K5: depthwise 3x3 conv + BN1 + GELU -> convx; fused 12-ch spatial-gate MLP
// -> sig_sp. grid (W/16, H/16, B), block (16,16) = 1 thread/pixel, channels
// chunked by 16 through an 18x18 LDS halo tile.
__global__ __launch_bounds__(256) void k_conv(const float* __restrict__ vbuf,
                                              const float* __restrict__ dw_w,
                                              const float* __restrict__ dw_b,
                                              const float* __restrict__ bn1_g,
                                              const float* __restrict__ bn1_b,
                                              const float* __restrict__ bn1_m,
                                              const float* __restrict__ bn1_v,
                                              const float* __restrict__ si_w1,
                                              const float* __restrict__ si_b1,
                                              const float* __restrict__ bn3_g,
                                              const float* __restrict__ bn3_b,
                                              const float* __restrict__ bn3_m,
                                              const float* __restrict__ bn3_v,
                                              const float* __restrict__ si_w2,
                                              const float* __restrict__ si_b2,
                                              float* __restrict__ convx,
                                              float* __restrict__ sig_sp)
{
    __shared__ float vh[16 * 324];     // 16ch x 18x18 halo
    __shared__ float sw1[12 * 192];
    __shared__ float dww[16 * 9];
    __shared__ float scl[16], shf[16];
    const int tx = threadIdx.x, ty = threadIdx.y;
    const int tid = ty * 16 + tx;
    const int x0 = blockIdx.x * 16, y0 = blockIdx.y * 16, b = blockIdx.z;
    for (int e = tid; e < 12 * 192; e += 256) sw1[e] = si_w1[e];
    float sm[12];
#pragma unroll
    for (int o = 0; o < 12; ++o) sm[o] = 0.f;
    const int gx = x0 + tx, gy = y0 + ty;
    for (int cc = 0; cc < 12; ++cc) {
        const int ch0 = cc * 16;
        __syncthreads();
        for (int e = tid; e < 16 * 324; e += 256) {
            int ch = e / 324, rem = e - ch * 324;
            int yy = rem / 18, xx = rem - yy * 18;
            int sy = y0 - 1 + yy, sx = x0 - 1 + xx;
            float v = 0.f;
            if (sy >= 0 && sy < Him && sx >= 0 && sx < Wim)
                v = vbuf[((size_t)b * Cc + ch0 + ch) * Ntok + sy * Wim + sx];
            vh[e] = v;
        }
        if (tid < 144) {
            dww[tid] = dw_w[ch0 * 9 + tid];
        } else if (tid < 160) {
            int ch = ch0 + tid - 144;
            float sc = bn1_g[ch] / sqrtf(bn1_v[ch] + EPSBN);
            scl[tid - 144] = sc;
            // BN applied to (conv + dw_b): fold conv bias into shift
            shf[tid - 144] = (dw_b[ch] - bn1_m[ch]) * sc + bn1_b[ch];
        }
        __syncthreads();
#pragma unroll 4
        for (int c = 0; c < 16; ++c) {
            const float* vp = vh + c * 324 + ty * 18 + tx;
            float conv =
                vp[0]  * dww[c * 9 + 0] + vp[1]  * dww[c * 9 + 1] + vp[2]  * dww[c * 9 + 2] +
                vp[18] * dww[c * 9 + 3] + vp[19] * dww[c * 9 + 4] + vp[20] * dww[c * 9 + 5] +
                vp[36] * dww[c * 9 + 6] + vp[37] * dww[c * 9 + 7] + vp[38] * dww[c * 9 + 8];
            float val = gelu_f(conv * scl[c] + shf[c]);
            convx[((size_t)b * Cc + ch0 + c) * Ntok + gy * Wim + gx] = val;
#pragma unroll
            for (int o = 0; o < 12; ++o) sm[o] = fmaf(sw1[o * 192 + ch0 + c], val, sm[o]);
        }
    }
    float sp = si_b2[0];
#pragma unroll
    for (int o = 0; o < 12; ++o) {
        float z = sm[o] + si_b1[o];
        float sc = bn3_g[o] / sqrtf(bn3_v[o] + EPSBN);
        z = z * sc + (bn3_b[o] - bn3_m[o] * sc);
        sp = fmaf(si_w2[o], gelu_f(z), sp);
    }
    sig_sp[b * Ntok + gy * Wim + gx] = sigmoid_f(sp);
}

// K6: fused epilogue. grid (N/64, B). Builds gated comb = att_x*sig_sp +
// conv_x*sig_ch in LDS (att_x computed on the fly from the 24x24 attn mats,
// never hits HBM), then 64x192x192 GEMM with proj_w.
__global__ __launch_bounds__(256) void k_final(const float* __restrict__ vbuf,
                                               const float* __restrict__ convx,
                                               const float* __restrict__ attn,
                                               const float* __restrict__ sig_ch,
                                               const float* __restrict__ sig_sp,
                                               const float* __restrict__ proj_w,
                                               const float* __restrict__ proj_b,
                                               float* __restrict__ out)
{
    __shared__ float comb[64 * 193];
    __shared__ float vh[64 * 25];
    __shared__ float ah[576];          // attn transposed [d][c]
    __shared__ float ssp[64];
    __shared__ float sch[192];
    const int t = threadIdx.x;
    const int n0 = blockIdx.x * 64;
    const int b = blockIdx.y;
    if (t < 64) ssp[t] = sig_sp[b * Ntok + n0 + t];
    if (t < 192) sch[t] = sig_ch[b * Cc + t];
    for (int h = 0; h < NHEADS; ++h) {
        __syncthreads();
        for (int e = t; e < 24 * 64; e += 256) {
            int d = e >> 6, n = e & 63;
            vh[n * 25 + d] = vbuf[((size_t)b * Cc + h * HDim + d) * Ntok + n0 + n];
        }
        for (int e = t; e < 576; e += 256) {
            int d = e / 24, c = e - d * 24;
            ah[e] = attn[(size_t)(b * NHEADS + h) * 576 + c * 24 + d];
        }
        __syncthreads();
        for (int e = t; e < 64 * 24; e += 256) {
            int n = e / 24, c = e - n * 24;
            float a = 0.f;
#pragma unroll
            for (int d = 0; d < 24; ++d) a = fmaf(ah[d * 24 + c], vh[n * 25 + d], a);
            comb[n * 193 + h * HDim + c] = a * ssp[n];
        }
    }
    __syncthreads();
    for (int e = t; e < 64 * 192; e += 256) {
        int ch = e >> 6, n = e & 63;   // coalesced convx read
        comb[n * 193 + ch] += convx[((size_t)b * Cc + ch) * Ntok + n0 + n] * sch[ch];
    }
    __syncthreads();
    const int tx = t & 15, ty = t >> 4;
    const int r0 = ty * 4, c0 = tx * 12;
    float acc[4][12];
#pragma unroll
    for (int i = 0; i < 4; ++i)
#pragma unroll
        for (int j = 0; j < 12; ++j) acc[i][j] = 0.f;
    for (int kk = 0; kk < 192; ++kk) {
        float a0 = comb[(r0 + 0) * 193 + kk];
        float a1 = comb[(r0 + 1) * 193 + kk];
        float a2 = comb[(r0 + 2) * 193 + kk];
        float a3 = comb[(r0 + 3) * 193 + kk];
        const float4* wp = (const float4*)(proj_w + (size_t)kk * 192 + c0);
        float4 b0 = wp[0], b1 = wp[1], b2 = wp[2];
        float bb[12] = {b0.x, b0.y, b0.z, b0.w, b1.x, b1.y, b1.z, b1.w,
                        b2.x, b2.y, b2.z, b2.w};
#pragma unroll
        for (int j = 0; j < 12; ++j) {
            acc[0][j] = fmaf(a0, bb[j], acc[0][j]);
            acc[1][j] = fmaf(a1, bb[j], acc[1][j]);
            acc[2][j] = fmaf(a2, bb[j], acc[2][j]);
            acc[3][j] = fmaf(a3, bb[j], acc[3][j]);
        }
    }
    float pb[12];
#pragma unroll
    for (int j = 0; j < 12; ++j) pb[j] = proj_b[c0 + j];
    float* ob = out + ((size_t)b * Ntok + n0) * Cc;
#pragma unroll
    for (int i = 0; i < 4; ++i) {
        float4 o0 = make_float4(acc[i][0] + pb[0], acc[i][1] + pb[1],
                                acc[i][2] + pb[2], acc[i][3] + pb[3]);
        float4 o1 = make_float4(acc[i][4] + pb[4], acc[i][5] + pb[5],
                                acc[i][6] + pb[6], acc[i][7] + pb[7]);
        float4 o2 = make_float4(acc[i][8] + pb[8], acc[i][9] + pb[9],
                                acc[i][10] + pb[10], acc[i][11] + pb[11]);
        float4* op = (float4*)(ob + (size_t)(r0 + i) * Cc + c0);
        op[0] = o0; op[1] = o1; op[2] = o2;
    }
}

extern "C" void kernel_launch(void* const* d_in, const int* in_sizes, int n_in,
                              void* d_out, int out_size, void* d_ws, size_t ws_size,
                              hipStream_t stream)
{
    const float* x      = (const float*)d_in[0];
    // d_in[1], d_in[2]: H, W scalars (fixed at 128) - unused
    const float* w_qkv  = (const float*)d_in[3];
    const float* temperature = (const float*)d_in[4];
    const float* dw_w   = (const float*)d_in[5];
    const float* dw_b   = (const float*)d_in[6];
    const float* bn1_g  = (const float*)d_in[7];
    const float* bn1_b  = (const float*)d_in[8];
    const float* bn1_m  = (const float*)d_in[9];
    const float* bn1_v  = (const float*)d_in[10];
    const float* ci_w1  = (const float*)d_in[11];
    const float* ci_b1  = (const float*)d_in[12];
    const float* bn2_g  = (const float*)d_in[13];
    const float* bn2_b  = (const float*)d_in[14];
    const float* bn2_m  = (const float*)d_in[15];
    const float* bn2_v  = (const float*)d_in[16];
    const float* ci_w2  = (const float*)d_in[17];
    const float* ci_b2  = (const float*)d_in[18];
    const float* si_w1  = (const float*)d_in[19];
    const float* si_b1  = (const float*)d_in[20];
    const float* bn3_g  = (const float*)d_in[21];
    const float* bn3_b  = (const float*)d_in[22];
    const float* bn3_m  = (const float*)d_in[23];
    const float* bn3_v  = (const float*)d_in[24];
    const float* si_w2  = (const float*)d_in[25];
    const float* si_b2  = (const float*)d_in[26];
    const float* proj_w = (const float*)d_in[27];
    const float* proj_b = (const float*)d_in[28];

    float* ws = (float*)d_ws;
    const size_t BCN = (size_t)Bb * Cc * Ntok;      // 25,165,824
    float* qbuf  = ws;
    float* kbuf  = ws + BCN;
    float* vbuf  = ws + 2 * BCN;
    float* gram  = ws + 3 * BCN;                    // 36864
    float* ssq_q = gram + 36864;                    // 1536
    float* ssq_k = ssq_q + 1536;                    // 1536
    float* vmean = ssq_k + 1536;                    // 1536
    float* attn  = vmean + 1536;                    // 36864
    float* sig_ch = attn + 36864;                   // 1536
    float* sig_sp = sig_ch + 1536;                  // 131072
    float* convx = qbuf;   // q region is dead after k_gram -> reuse for conv_x
    float* out = (float*)d_out;

    // zero the atomic accumulators (ws is poisoned 0xAA before every launch)
    hipMemsetAsync(gram, 0, (36864 + 1536 + 1536) * sizeof(float), stream);

    k_qkv<<<dim3(Ntok / 64, Bb, 3), 256, 0, stream>>>(x, w_qkv, ws);
    k_gram<<<dim3(Ntok / 256, NHEADS, Bb), 256, 0, stream>>>(qbuf, kbuf, gram, ssq_q, ssq_k);
    k_vmean<<<dim3(Cc, Bb), 256, 0, stream>>>(vbuf, vmean);
    k_attn<<<dim3(Bb), 256, 0, stream>>>(gram, ssq_q, ssq_k, temperature, vmean,
                                         ci_w1, ci_b1, bn2_g, bn2_b, bn2_m, bn2_v,
                                         ci_w2, ci_b2, attn, sig_ch);
    k_conv<<<dim3(Wim / 16, Him / 16, Bb), dim3(16, 16), 0, stream>>>(
        vbuf, dw_w, dw_b, bn1_g, bn1_b, bn1_m, bn1_v,
        si_w1, si_b1, bn3_g, bn3_b, bn3_m, bn3_v, si_w2, si_b2, convx, sig_sp);
    k_final<<<dim3(Ntok / 64, Bb), 256, 0, stream>>>(vbuf, convx, attn, sig_ch, sig_sp,
                                                     proj_w, proj_b, out);
}

// Round 2
// 956.827 us; speedup vs baseline: 1.3023x; 1.3023x over previous
//
#include <hip/hip_runtime.h>
#include <math.h>

// Problem constants (fixed by setup_inputs)
#define Bb 8
#define Cc 192
#define NHEADS 8
#define HDim 24
#define Him 128
#define Wim 128
#define Ntok 16384   // H*W
#define EPSBN 1e-5f

typedef __bf16 bf16x8 __attribute__((ext_vector_type(8)));
typedef float  f32x4  __attribute__((ext_vector_type(4)));

static __device__ __forceinline__ float gelu_f(float v) {
    return 0.5f * v * (1.0f + erff(v * 0.70710678118654752f));
}
static __device__ __forceinline__ float sigmoid_f(float v) {
    return 1.0f / (1.0f + expf(-v));
}

// ---------------------------------------------------------------------------
// K0: one-time prep: transpose w_qkv (192x576 fp32) into bf16 hi/lo planes in
// [col][k] layout (k contiguous -> MFMA B-fragment reads are ds_read_b128).
// Stored in the tail of d_out (dead until k_final overwrites it at the end).
// ---------------------------------------------------------------------------
__global__ __launch_bounds__(256) void k_wprep(const float* __restrict__ w,
                                               __bf16* __restrict__ wt)
{
    int idx = blockIdx.x * 256 + threadIdx.x;   // 192*576 = 110592 total
    if (idx >= 192 * 576) return;
    int k = idx / 576, c = idx % 576;           // coalesced read over c
    float v = w[idx];
    __bf16 h = (__bf16)v;
    __bf16 l = (__bf16)(v - (float)h);
    wt[c * 192 + k] = h;
    wt[110592 + c * 192 + k] = l;
}

// ---------------------------------------------------------------------------
// K1: qkv projection via split-bf16 MFMA (x=xh+xl, w=wh+wl; keep hh+hl+lh ->
// fp32-equivalent precision at the 2.4PF bf16 pipe). Block = 128 tokens x 192
// cols of section sec. K chunked by 32. A staged [row][k] stride 40 bf16,
// B staged [col][k] stride 40 (2-way bank aliasing = free). Wave = 64 rows x
// 96 cols = 4x6 tiles of 16x16x32. Output stored transposed (B,C,N) via
// float4 (C-layout rows = 4 consecutive tokens per lane). v-section blocks
// also accumulate per-channel sums (replaces k_vmean).
// ---------------------------------------------------------------------------
__global__ __launch_bounds__(256, 2) void k_qkv_mfma(const float* __restrict__ x,
                                                     const __bf16* __restrict__ wt,
                                                     float* __restrict__ qkv,
                                                     float* __restrict__ vsum)
{
    __shared__ __align__(16) __bf16 Ah[128 * 40];
    __shared__ __align__(16) __bf16 Al[128 * 40];
    __shared__ __align__(16) __bf16 Bh[192 * 40];
    __shared__ __align__(16) __bf16 Bl[192 * 40];

    const int t = threadIdx.x;
    const int lane = t & 63, wave = t >> 6;
    const int n0 = blockIdx.x * 128;
    const int b = blockIdx.y;
    const int sec = blockIdx.z;
    const int row_base = (wave & 1) * 64;    // token rows within tile
    const int col_base = (wave >> 1) * 96;   // w cols within section
    const int m16 = lane & 15, q = lane >> 4;

    f32x4 acc[4][6];
#pragma unroll
    for (int rt = 0; rt < 4; ++rt)
#pragma unroll
        for (int ct = 0; ct < 6; ++ct)
#pragma unroll
            for (int j = 0; j < 4; ++j) acc[rt][ct][j] = 0.f;

    // staging assignments (constant across chunks)
    const int ar = t >> 1, ahalf = t & 1;    // A: thread -> (row, 16-col half)
    const float* xrow = x + ((size_t)b * Ntok + n0 + ar) * Cc + ahalf * 16;

    for (int kc = 0; kc < 6; ++kc) {
        // ---- stage A: 128 rows x 32 k, fp32 -> bf16 hi/lo ----
        {
            const float4* xp4 = (const float4*)(xrow + kc * 32);
            float xv[16];
            float4 u;
            u = xp4[0]; xv[0] = u.x; xv[1] = u.y; xv[2]  = u.z; xv[3]  = u.w;
            u = xp4[1]; xv[4] = u.x; xv[5] = u.y; xv[6]  = u.z; xv[7]  = u.w;
            u = xp4[2]; xv[8] = u.x; xv[9] = u.y; xv[10] = u.z; xv[11] = u.w;
            u = xp4[3]; xv[12] = u.x; xv[13] = u.y; xv[14] = u.z; xv[15] = u.w;
            bf16x8 vh0, vh1, vl0, vl1;
#pragma unroll
            for (int j = 0; j < 8; ++j) {
                float v = xv[j];
                __bf16 h = (__bf16)v;
                vh0[j] = h; vl0[j] = (__bf16)(v - (float)h);
            }
#pragma unroll
            for (int j = 0; j < 8; ++j) {
                float v = xv[8 + j];
                __bf16 h = (__bf16)v;
                vh1[j] = h; vl1[j] = (__bf16)(v - (float)h);
            }
            const int o = ar * 40 + ahalf * 16;
            *(bf16x8*)&Ah[o] = vh0; *(bf16x8*)&Ah[o + 8] = vh1;
            *(bf16x8*)&Al[o] = vl0; *(bf16x8*)&Al[o + 8] = vl1;
        }
        // ---- stage B: 192 cols x 32 k bf16 hi/lo (already transposed) ----
#pragma unroll
        for (int i = 0; i < 3; ++i) {
            int f = i * 256 + t;                 // 768 chunks of 8 bf16
            int n = f >> 2, k8 = (f & 3) << 3;
            const __bf16* src = wt + ((size_t)(sec * 192 + n)) * 192 + kc * 32 + k8;
            bf16x8 vh = *(const bf16x8*)src;
            bf16x8 vl = *(const bf16x8*)(src + 110592);
            *(bf16x8*)&Bh[n * 40 + k8] = vh;
            *(bf16x8*)&Bl[n * 40 + k8] = vl;
        }
        __syncthreads();

        // ---- fragment loads ----
        bf16x8 fah[4], fal[4], fbh[6], fbl[6];
#pragma unroll
        for (int rt = 0; rt < 4; ++rt) {
            int o = (row_base + rt * 16 + m16) * 40 + q * 8;
            fah[rt] = *(const bf16x8*)&Ah[o];
            fal[rt] = *(const bf16x8*)&Al[o];
        }
#pragma unroll
        for (int ct = 0; ct < 6; ++ct) {
            int o = (col_base + ct * 16 + m16) * 40 + q * 8;
            fbh[ct] = *(const bf16x8*)&Bh[o];
            fbl[ct] = *(const bf16x8*)&Bl[o];
        }
        // ---- MFMA: hh + hl + lh ----
#pragma unroll
        for (int rt = 0; rt < 4; ++rt)
#pragma unroll
            for (int ct = 0; ct < 6; ++ct) {
                acc[rt][ct] = __builtin_amdgcn_mfma_f32_16x16x32_bf16(
                    fah[rt], fbh[ct], acc[rt][ct], 0, 0, 0);
                acc[rt][ct] = __builtin_amdgcn_mfma_f32_16x16x32_bf16(
                    fah[rt], fbl[ct], acc[rt][ct], 0, 0, 0);
                acc[rt][ct] = __builtin_amdgcn_mfma_f32_16x16x32_bf16(
                    fal[rt], fbh[ct], acc[rt][ct], 0, 0, 0);
            }
        __syncthreads();
    }

    // ---- epilogue: store transposed (ch-major); 4 consecutive tokens/lane ----
    const size_t obase = (size_t)sec * ((size_t)Bb * Cc * Ntok)
                       + (size_t)b * Cc * (size_t)Ntok;
#pragma unroll
    for (int rt = 0; rt < 4; ++rt)
#pragma unroll
        for (int ct = 0; ct < 6; ++ct) {
            int token = n0 + row_base + rt * 16 + q * 4;
            int col = col_base + ct * 16 + m16;
            float4 o = make_float4(acc[rt][ct][0], acc[rt][ct][1],
                                   acc[rt][ct][2], acc[rt][ct][3]);
            *(float4*)(qkv + obase + (size_t)col * Ntok + token) = o;
        }

    // ---- fused v channel-sum (replaces k_vmean); sec uniform per block ----
    if (sec == 2) {
#pragma unroll
        for (int ct = 0; ct < 6; ++ct) {
            float s = 0.f;
#pragma unroll
            for (int rt = 0; rt < 4; ++rt)
                s += acc[rt][ct][0] + acc[rt][ct][1] + acc[rt][ct][2] + acc[rt][ct][3];
            s += __shfl_xor(s, 16, 64);
            s += __shfl_xor(s, 32, 64);
            if (q == 0)
                atomicAdd(vsum + b * Cc + col_base + ct * 16 + m16, s);
        }
    }
}

// ---------------------------------------------------------------------------
// K2: Gram matrices + sum-of-squares. grid (N/256, HEADS, B).
// ---------------------------------------------------------------------------
__global__ __launch_bounds__(256) void k_gram(const float* __restrict__ qbuf,
                                              const float* __restrict__ kbuf,
                                              float* __restrict__ gram,
                                              float* __restrict__ ssq_q,
                                              float* __restrict__ ssq_k)
{
    __shared__ float qc[24 * 257];
    __shared__ float kc[24 * 257];
    const int t = threadIdx.x;
    const int n0 = blockIdx.x * 256;
    const int h = blockIdx.y;
    const int b = blockIdx.z;
    const float* qb = qbuf + ((size_t)b * Cc + h * HDim) * Ntok + n0;
    const float* kb = kbuf + ((size_t)b * Cc + h * HDim) * Ntok + n0;
    for (int e = t; e < 24 * 256; e += 256) {
        int c = e >> 8, n = e & 255;
        qc[c * 257 + n] = qb[(size_t)c * Ntok + n];
        kc[c * 257 + n] = kb[(size_t)c * Ntok + n];
    }
    __syncthreads();
    float g0 = 0.f, g1 = 0.f, g2 = 0.f;
    const int c1 = t / 24, d1 = t % 24;
    const int e2 = t + 256; const int c2 = e2 / 24, d2 = e2 % 24;
    const int e3 = t + 512;
    const int c3 = (t < 64) ? e3 / 24 : 0, d3 = (t < 64) ? e3 % 24 : 0;
    for (int n = 0; n < 256; ++n) {
        g0 = fmaf(qc[c1 * 257 + n], kc[d1 * 257 + n], g0);
        g1 = fmaf(qc[c2 * 257 + n], kc[d2 * 257 + n], g1);
        g2 = fmaf(qc[c3 * 257 + n], kc[d3 * 257 + n], g2);
    }
    float* gp = gram + (size_t)(b * NHEADS + h) * 576;
    atomicAdd(gp + t, g0);
    atomicAdd(gp + e2, g1);
    if (t < 64) atomicAdd(gp + e3, g2);
    if (t < 24) {
        float s = 0.f;
        for (int n = 0; n < 256; ++n) { float v = qc[t * 257 + n]; s = fmaf(v, v, s); }
        atomicAdd(ssq_q + b * Cc + h * HDim + t, s);
    } else if (t < 48) {
        int d = t - 24; float s = 0.f;
        for (int n = 0; n < 256; ++n) { float v = kc[d * 257 + n]; s = fmaf(v, v, s); }
        atomicAdd(ssq_k + b * Cc + h * HDim + d, s);
    }
}

// K4: normalize gram -> softmax attn; pooled = attn @ vmean; channel-gate MLP.
// vmean now holds channel SUMS (from k_qkv_mfma) -> scale by 1/Ntok here.
__global__ __launch_bounds__(256) void k_attn(const float* __restrict__ gram,
                                              const float* __restrict__ ssq_q,
                                              const float* __restrict__ ssq_k,
                                              const float* __restrict__ temperature,
                                              const float* __restrict__ vmean,
                                              const float* __restrict__ ci_w1,
                                              const float* __restrict__ ci_b1,
                                              const float* __restrict__ bn2_g,
                                              const float* __restrict__ bn2_b,
                                              const float* __restrict__ bn2_m,
                                              const float* __restrict__ bn2_v,
                                              const float* __restrict__ ci_w2,
                                              const float* __restrict__ ci_b2,
                                              float* __restrict__ attn,
                                              float* __restrict__ sig_ch)
{
    __shared__ float pooled[192];
    __shared__ float cmv[24];
    const int b = blockIdx.x, t = threadIdx.x;
    if (t < 192) {
        int h = t / 24, c = t % 24;
        const float* gp = gram + (size_t)(b * NHEADS + h) * 576 + c * 24;
        float qn = fmaxf(sqrtf(ssq_q[b * Cc + h * HDim + c]), 1e-12f);
        float temp = temperature[h];
        float logit[24];
        float m = -1e30f;
#pragma unroll
        for (int d = 0; d < 24; ++d) {
            float kn = fmaxf(sqrtf(ssq_k[b * Cc + h * HDim + d]), 1e-12f);
            float l = gp[d] / (qn * kn) * temp;
            logit[d] = l; m = fmaxf(m, l);
        }
        float s = 0.f;
#pragma unroll
        for (int d = 0; d < 24; ++d) { float e = expf(logit[d] - m); logit[d] = e; s += e; }
        float inv = 1.f / s;
        float pool = 0.f;
        float* ap = attn + (size_t)(b * NHEADS + h) * 576 + c * 24;
#pragma unroll
        for (int d = 0; d < 24; ++d) {
            float a = logit[d] * inv;
            ap[d] = a;
            pool = fmaf(a, vmean[b * Cc + h * HDim + d], pool);
        }
        pooled[h * 24 + c] = pool * (1.0f / (float)Ntok);
    }
    __syncthreads();
    if (t < 24) {
        float z = ci_b1[t];
        for (int c = 0; c < 192; ++c) z = fmaf(ci_w1[t * 192 + c], pooled[c], z);
        float sc = bn2_g[t] / sqrtf(bn2_v[t] + EPSBN);
        z = z * sc + (bn2_b[t] - bn2_m[t] * sc);
        cmv[t] = gelu_f(z);
    }
    __syncthreads();
    if (t < 192) {
        float z = ci_b2[t];
#pragma unroll
        for (int o = 0; o < 24; ++o) z = fmaf(ci_w2[t * 24 + o], cmv[o], z);
        sig_ch[b * Cc + t] = sigmoid_f(z);
    }
}

// K5: depthwise 3x3 conv + BN1 + GELU -> convx; fused spatial-gate MLP.
__global__ __launch_bounds__(256) void k_conv(const float* __restrict__ vbuf,
                                              const float* __restrict__ dw_w,
                                              const float* __restrict__ dw_b,
                                              const float* __restrict__ bn1_g,
                                              const float* __restrict__ bn1_b,
                                              const float* __restrict__ bn1_m,
                                              const float* __restrict__ bn1_v,
                                              const float* __restrict__ si_w1,
                                              const float* __restrict__ si_b1,
                                              const float* __restrict__ bn3_g,
                                              const float* __restrict__ bn3_b,
                                              const float* __restrict__ bn3_m,
                                              const float* __restrict__ bn3_v,
                                              const float* __restrict__ si_w2,
                                              const float* __restrict__ si_b2,
                                              float* __restrict__ convx,
                                              float* __restrict__ sig_sp)
{
    __shared__ float vh[16 * 324];     // 16ch x 18x18 halo
    __shared__ float sw1[12 * 192];
    __shared__ float dww[16 * 9];
    __shared__ float scl[16], shf[16];
    const int tx = threadIdx.x, ty = threadIdx.y;
    const int tid = ty * 16 + tx;
    const int x0 = blockIdx.x * 16, y0 = blockIdx.y * 16, b = blockIdx.z;
    for (int e = tid; e < 12 * 192; e += 256) sw1[e] = si_w1[e];
    float sm[12];
#pragma unroll
    for (int o = 0; o < 12; ++o) sm[o] = 0.f;
    const int gx = x0 + tx, gy = y0 + ty;
    for (int cc = 0; cc < 12; ++cc) {
        const int ch0 = cc * 16;
        __syncthreads();
        for (int e = tid; e < 16 * 324; e += 256) {
            int ch = e / 324, rem = e - ch * 324;
            int yy = rem / 18, xx = rem - yy * 18;
            int sy = y0 - 1 + yy, sx = x0 - 1 + xx;
            float v = 0.f;
            if (sy >= 0 && sy < Him && sx >= 0 && sx < Wim)
                v = vbuf[((size_t)b * Cc + ch0 + ch) * Ntok + sy * Wim + sx];
            vh[e] = v;
        }
        if (tid < 144) {
            dww[tid] = dw_w[ch0 * 9 + tid];
        } else if (tid < 160) {
            int ch = ch0 + tid - 144;
            float sc = bn1_g[ch] / sqrtf(bn1_v[ch] + EPSBN);
            scl[tid - 144] = sc;
            shf[tid - 144] = (dw_b[ch] - bn1_m[ch]) * sc + bn1_b[ch];
        }
        __syncthreads();
#pragma unroll 4
        for (int c = 0; c < 16; ++c) {
            const float* vp = vh + c * 324 + ty * 18 + tx;
            float conv =
                vp[0]  * dww[c * 9 + 0] + vp[1]  * dww[c * 9 + 1] + vp[2]  * dww[c * 9 + 2] +
                vp[18] * dww[c * 9 + 3] + vp[19] * dww[c * 9 + 4] + vp[20] * dww[c * 9 + 5] +
                vp[36] * dww[c * 9 + 6] + vp[37] * dww[c * 9 + 7] + vp[38] * dww[c * 9 + 8];
            float val = gelu_f(conv * scl[c] + shf[c]);
            convx[((size_t)b * Cc + ch0 + c) * Ntok + gy * Wim + gx] = val;
#pragma unroll
            for (int o = 0; o < 12; ++o) sm[o] = fmaf(sw1[o * 192 + ch0 + c], val, sm[o]);
        }
    }
    float sp = si_b2[0];
#pragma unroll
    for (int o = 0; o < 12; ++o) {
        float z = sm[o] + si_b1[o];
        float sc = bn3_g[o] / sqrtf(bn3_v[o] + EPSBN);
        z = z * sc + (bn3_b[o] - bn3_m[o] * sc);
        sp = fmaf(si_w2[o], gelu_f(z), sp);
    }
    sig_sp[b * Ntok + gy * Wim + gx] = sigmoid_f(sp);
}

// K6: fused epilogue (unchanged this round; MFMA conversion next round).
__global__ __launch_bounds__(256) void k_final(const float* __restrict__ vbuf,
                                               const float* __restrict__ convx,
                                               const float* __restrict__ attn,
                                               const float* __restrict__ sig_ch,
                                               const float* __restrict__ sig_sp,
                                               const float* __restrict__ proj_w,
                                               const float* __restrict__ proj_b,
                                               float* __restrict__ out)
{
    __shared__ float comb[64 * 193];
    __shared__ float vh[64 * 25];
    __shared__ float ah[576];          // attn transposed [d][c]
    __shared__ float ssp[64];
    __shared__ float sch[192];
    const int t = threadIdx.x;
    const int n0 = blockIdx.x * 64;
    const int b = blockIdx.y;
    if (t < 64) ssp[t] = sig_sp[b * Ntok + n0 + t];
    if (t < 192) sch[t] = sig_ch[b * Cc + t];
    for (int h = 0; h < NHEADS; ++h) {
        __syncthreads();
        for (int e = t; e < 24 * 64; e += 256) {
            int d = e >> 6, n = e & 63;
            vh[n * 25 + d] = vbuf[((size_t)b * Cc + h * HDim + d) * Ntok + n0 + n];
        }
        for (int e = t; e < 576; e += 256) {
            int d = e / 24, c = e - d * 24;
            ah[e] = attn[(size_t)(b * NHEADS + h) * 576 + c * 24 + d];
        }
        __syncthreads();
        for (int e = t; e < 64 * 24; e += 256) {
            int n = e / 24, c = e - n * 24;
            float a = 0.f;
#pragma unroll
            for (int d = 0; d < 24; ++d) a = fmaf(ah[d * 24 + c], vh[n * 25 + d], a);
            comb[n * 193 + h * HDim + c] = a * ssp[n];
        }
    }
    __syncthreads();
    for (int e = t; e < 64 * 192; e += 256) {
        int ch = e >> 6, n = e & 63;   // coalesced convx read
        comb[n * 193 + ch] += convx[((size_t)b * Cc + ch) * Ntok + n0 + n] * sch[ch];
    }
    __syncthreads();
    const int tx = t & 15, ty = t >> 4;
    const int r0 = ty * 4, c0 = tx * 12;
    float acc[4][12];
#pragma unroll
    for (int i = 0; i < 4; ++i)
#pragma unroll
        for (int j = 0; j < 12; ++j) acc[i][j] = 0.f;
    for (int kk = 0; kk < 192; ++kk) {
        float a0 = comb[(r0 + 0) * 193 + kk];
        float a1 = comb[(r0 + 1) * 193 + kk];
        float a2 = comb[(r0 + 2) * 193 + kk];
        float a3 = comb[(r0 + 3) * 193 + kk];
        const float4* wp = (const float4*)(proj_w + (size_t)kk * 192 + c0);
        float4 b0 = wp[0], b1 = wp[1], b2 = wp[2];
        float bb[12] = {b0.x, b0.y, b0.z, b0.w, b1.x, b1.y, b1.z, b1.w,
                        b2.x, b2.y, b2.z, b2.w};
#pragma unroll
        for (int j = 0; j < 12; ++j) {
            acc[0][j] = fmaf(a0, bb[j], acc[0][j]);
            acc[1][j] = fmaf(a1, bb[j], acc[1][j]);
            acc[2][j] = fmaf(a2, bb[j], acc[2][j]);
            acc[3][j] = fmaf(a3, bb[j], acc[3][j]);
        }
    }
    float pb[12];
#pragma unroll
    for (int j = 0; j < 12; ++j) pb[j] = proj_b[c0 + j];
    float* ob = out + ((size_t)b * Ntok + n0) * Cc;
#pragma unroll
    for (int i = 0; i < 4; ++i) {
        float4 o0 = make_float4(acc[i][0] + pb[0], acc[i][1] + pb[1],
                                acc[i][2] + pb[2], acc[i][3] + pb[3]);
        float4 o1 = make_float4(acc[i][4] + pb[4], acc[i][5] + pb[5],
                                acc[i][6] + pb[6], acc[i][7] + pb[7]);
        float4 o2 = make_float4(acc[i][8] + pb[8], acc[i][9] + pb[9],
                                acc[i][10] + pb[10], acc[i][11] + pb[11]);
        float4* op = (float4*)(ob + (size_t)(r0 + i) * Cc + c0);
        op[0] = o0; op[1] = o1; op[2] = o2;
    }
}

extern "C" void kernel_launch(void* const* d_in, const int* in_sizes, int n_in,
                              void* d_out, int out_size, void* d_ws, size_t ws_size,
                              hipStream_t stream)
{
    const float* x      = (const float*)d_in[0];
    const float* w_qkv  = (const float*)d_in[3];
    const float* temperature = (const float*)d_in[4];
    const float* dw_w   = (const float*)d_in[5];
    const float* dw_b   = (const float*)d_in[6];
    const float* bn1_g  = (const float*)d_in[7];
    const float* bn1_b  = (const float*)d_in[8];
    const float* bn1_m  = (const float*)d_in[9];
    const float* bn1_v  = (const float*)d_in[10];
    const float* ci_w1  = (const float*)d_in[11];
    const float* ci_b1  = (const float*)d_in[12];
    const float* bn2_g  = (const float*)d_in[13];
    const float* bn2_b  = (const float*)d_in[14];
    const float* bn2_m  = (const float*)d_in[15];
    const float* bn2_v  = (const float*)d_in[16];
    const float* ci_w2  = (const float*)d_in[17];
    const float* ci_b2  = (const float*)d_in[18];
    const float* si_w1  = (const float*)d_in[19];
    const float* si_b1  = (const float*)d_in[20];
    const float* bn3_g  = (const float*)d_in[21];
    const float* bn3_b  = (const float*)d_in[22];
    const float* bn3_m  = (const float*)d_in[23];
    const float* bn3_v  = (const float*)d_in[24];
    const float* si_w2  = (const float*)d_in[25];
    const float* si_b2  = (const float*)d_in[26];
    const float* proj_w = (const float*)d_in[27];
    const float* proj_b = (const float*)d_in[28];

    float* ws = (float*)d_ws;
    const size_t BCN = (size_t)Bb * Cc * Ntok;      // 25,165,824
    float* qbuf  = ws;
    float* kbuf  = ws + BCN;
    float* vbuf  = ws + 2 * BCN;
    float* gram  = ws + 3 * BCN;                    // 36864
    float* ssq_q = gram + 36864;                    // 1536
    float* ssq_k = ssq_q + 1536;                    // 1536
    float* vmean = ssq_k + 1536;                    // 1536 (holds channel SUMS)
    float* attn  = vmean + 1536;                    // 36864
    float* sig_ch = attn + 36864;                   // 1536
    float* sig_sp = sig_ch + 1536;                  // 131072
    float* convx = qbuf;   // q region is dead after k_gram -> reuse for conv_x
    float* out = (float*)d_out;

    // bf16 hi/lo transposed w_qkv lives in the tail of d_out (110592 floats =
    // 442 KB). Dead region until k_final overwrites it at the very end.
    __bf16* wt = (__bf16*)(out + BCN - 110592);

    // zero atomic accumulators: gram + ssq_q + ssq_k + vmean(sums)
    hipMemsetAsync(gram, 0, (36864 + 3 * 1536) * sizeof(float), stream);

    k_wprep<<<dim3(432), 256, 0, stream>>>(w_qkv, wt);
    k_qkv_mfma<<<dim3(Ntok / 128, Bb, 3), 256, 0, stream>>>(x, wt, ws, vmean);
    k_gram<<<dim3(Ntok / 256, NHEADS, Bb), 256, 0, stream>>>(qbuf, kbuf, gram, ssq_q, ssq_k);
    k_attn<<<dim3(Bb), 256, 0, stream>>>(gram, ssq_q, ssq_k, temperature, vmean,
                                         ci_w1, ci_b1, bn2_g, bn2_b, bn2_m, bn2_v,
                                         ci_w2, ci_b2, attn, sig_ch);
    k_conv<<<dim3(Wim / 16, Him / 16, Bb), dim3(16, 16), 0, stream>>>(
        vbuf, dw_w, dw_b, bn1_g, bn1_b, bn1_m, bn1_v,
        si_w1, si_b1, bn3_g, bn3_b, bn3_m, bn3_v, si_w2, si_b2, convx, sig_sp);
    k_final<<<dim3(Ntok / 64, Bb), 256, 0, stream>>>(vbuf, convx, attn, sig_ch, sig_sp,
                                                     proj_w, proj_b, out);
}

// Round 3
// 736.008 us; speedup vs baseline: 1.6930x; 1.3000x over previous
//
#include <hip/hip_runtime.h>
#include <math.h>

// Problem constants (fixed by setup_inputs)
#define Bb 8
#define Cc 192
#define NHEADS 8
#define HDim 24
#define Him 128
#define Wim 128
#define Ntok 16384   // H*W
#define EPSBN 1e-5f

typedef __bf16 bf16x8 __attribute__((ext_vector_type(8)));
typedef float  f32x4  __attribute__((ext_vector_type(4)));

static __device__ __forceinline__ float gelu_f(float v) {
    return 0.5f * v * (1.0f + erff(v * 0.70710678118654752f));
}
static __device__ __forceinline__ float sigmoid_f(float v) {
    return 1.0f / (1.0f + expf(-v));
}
static __device__ __forceinline__ void split8(const float* xv, bf16x8& h8, bf16x8& l8) {
#pragma unroll
    for (int j = 0; j < 8; ++j) {
        float v = xv[j];
        __bf16 h = (__bf16)v;
        h8[j] = h;
        l8[j] = (__bf16)(v - (float)h);
    }
}

// ---------------------------------------------------------------------------
// K0: one-time prep: transpose w_qkv (192x576 fp32) into bf16 hi/lo planes in
// [col][k] layout. Stored in the tail of d_out (dead until k_final's final
// write, which happens long after k_qkv consumed it).
// ---------------------------------------------------------------------------
__global__ __launch_bounds__(256) void k_wprep(const float* __restrict__ w,
                                               __bf16* __restrict__ wt)
{
    int idx = blockIdx.x * 256 + threadIdx.x;   // 192*576 = 110592 total
    if (idx >= 192 * 576) return;
    int k = idx / 576, c = idx % 576;           // coalesced read over c
    float v = w[idx];
    __bf16 h = (__bf16)v;
    __bf16 l = (__bf16)(v - (float)h);
    wt[c * 192 + k] = h;
    wt[110592 + c * 192 + k] = l;
}

// ---------------------------------------------------------------------------
// K1: qkv projection via split-bf16 MFMA. Block = 128 tokens x 192 cols of
// section sec. Output transposed to (B,C,N). v-section blocks also
// accumulate per-channel sums (replaces k_vmean).
// ---------------------------------------------------------------------------
__global__ __launch_bounds__(256, 2) void k_qkv_mfma(const float* __restrict__ x,
                                                     const __bf16* __restrict__ wt,
                                                     float* __restrict__ qkv,
                                                     float* __restrict__ vsum)
{
    __shared__ __align__(16) __bf16 Ah[128 * 40];
    __shared__ __align__(16) __bf16 Al[128 * 40];
    __shared__ __align__(16) __bf16 Bh[192 * 40];
    __shared__ __align__(16) __bf16 Bl[192 * 40];

    const int t = threadIdx.x;
    const int lane = t & 63, wave = t >> 6;
    const int n0 = blockIdx.x * 128;
    const int b = blockIdx.y;
    const int sec = blockIdx.z;
    const int row_base = (wave & 1) * 64;    // token rows within tile
    const int col_base = (wave >> 1) * 96;   // w cols within section
    const int m16 = lane & 15, q = lane >> 4;

    f32x4 acc[4][6];
#pragma unroll
    for (int rt = 0; rt < 4; ++rt)
#pragma unroll
        for (int ct = 0; ct < 6; ++ct)
#pragma unroll
            for (int j = 0; j < 4; ++j) acc[rt][ct][j] = 0.f;

    const int ar = t >> 1, ahalf = t & 1;    // A: thread -> (row, 16-col half)
    const float* xrow = x + ((size_t)b * Ntok + n0 + ar) * Cc + ahalf * 16;

    for (int kc = 0; kc < 6; ++kc) {
        // ---- stage A: 128 rows x 32 k, fp32 -> bf16 hi/lo ----
        {
            const float4* xp4 = (const float4*)(xrow + kc * 32);
            float xv[16];
            float4 u;
            u = xp4[0]; xv[0] = u.x; xv[1] = u.y; xv[2]  = u.z; xv[3]  = u.w;
            u = xp4[1]; xv[4] = u.x; xv[5] = u.y; xv[6]  = u.z; xv[7]  = u.w;
            u = xp4[2]; xv[8] = u.x; xv[9] = u.y; xv[10] = u.z; xv[11] = u.w;
            u = xp4[3]; xv[12] = u.x; xv[13] = u.y; xv[14] = u.z; xv[15] = u.w;
            bf16x8 vh0, vh1, vl0, vl1;
            split8(xv, vh0, vl0);
            split8(xv + 8, vh1, vl1);
            const int o = ar * 40 + ahalf * 16;
            *(bf16x8*)&Ah[o] = vh0; *(bf16x8*)&Ah[o + 8] = vh1;
            *(bf16x8*)&Al[o] = vl0; *(bf16x8*)&Al[o + 8] = vl1;
        }
        // ---- stage B: 192 cols x 32 k bf16 hi/lo (pre-transposed) ----
#pragma unroll
        for (int i = 0; i < 3; ++i) {
            int f = i * 256 + t;                 // 768 chunks of 8 bf16
            int n = f >> 2, k8 = (f & 3) << 3;
            const __bf16* src = wt + ((size_t)(sec * 192 + n)) * 192 + kc * 32 + k8;
            bf16x8 vh = *(const bf16x8*)src;
            bf16x8 vl = *(const bf16x8*)(src + 110592);
            *(bf16x8*)&Bh[n * 40 + k8] = vh;
            *(bf16x8*)&Bl[n * 40 + k8] = vl;
        }
        __syncthreads();

        bf16x8 fah[4], fal[4], fbh[6], fbl[6];
#pragma unroll
        for (int rt = 0; rt < 4; ++rt) {
            int o = (row_base + rt * 16 + m16) * 40 + q * 8;
            fah[rt] = *(const bf16x8*)&Ah[o];
            fal[rt] = *(const bf16x8*)&Al[o];
        }
#pragma unroll
        for (int ct = 0; ct < 6; ++ct) {
            int o = (col_base + ct * 16 + m16) * 40 + q * 8;
            fbh[ct] = *(const bf16x8*)&Bh[o];
            fbl[ct] = *(const bf16x8*)&Bl[o];
        }
#pragma unroll
        for (int rt = 0; rt < 4; ++rt)
#pragma unroll
            for (int ct = 0; ct < 6; ++ct) {
                acc[rt][ct] = __builtin_amdgcn_mfma_f32_16x16x32_bf16(
                    fah[rt], fbh[ct], acc[rt][ct], 0, 0, 0);
                acc[rt][ct] = __builtin_amdgcn_mfma_f32_16x16x32_bf16(
                    fah[rt], fbl[ct], acc[rt][ct], 0, 0, 0);
                acc[rt][ct] = __builtin_amdgcn_mfma_f32_16x16x32_bf16(
                    fal[rt], fbh[ct], acc[rt][ct], 0, 0, 0);
            }
        __syncthreads();
    }

    // ---- epilogue: store transposed (ch-major); 4 consecutive tokens/lane ----
    const size_t obase = (size_t)sec * ((size_t)Bb * Cc * Ntok)
                       + (size_t)b * Cc * (size_t)Ntok;
#pragma unroll
    for (int rt = 0; rt < 4; ++rt)
#pragma unroll
        for (int ct = 0; ct < 6; ++ct) {
            int token = n0 + row_base + rt * 16 + q * 4;
            int col = col_base + ct * 16 + m16;
            float4 o = make_float4(acc[rt][ct][0], acc[rt][ct][1],
                                   acc[rt][ct][2], acc[rt][ct][3]);
            *(float4*)(qkv + obase + (size_t)col * Ntok + token) = o;
        }

    if (sec == 2) {
#pragma unroll
        for (int ct = 0; ct < 6; ++ct) {
            float s = 0.f;
#pragma unroll
            for (int rt = 0; rt < 4; ++rt)
                s += acc[rt][ct][0] + acc[rt][ct][1] + acc[rt][ct][2] + acc[rt][ct][3];
            s += __shfl_xor(s, 16, 64);
            s += __shfl_xor(s, 32, 64);
            if (q == 0)
                atomicAdd(vsum + b * Cc + col_base + ct * 16 + m16, s);
        }
    }
}

// ---------------------------------------------------------------------------
// K2: Gram matrices + sum-of-squares. grid (N/256, HEADS, B).
// ---------------------------------------------------------------------------
__global__ __launch_bounds__(256) void k_gram(const float* __restrict__ qbuf,
                                              const float* __restrict__ kbuf,
                                              float* __restrict__ gram,
                                              float* __restrict__ ssq_q,
                                              float* __restrict__ ssq_k)
{
    __shared__ float qc[24 * 257];
    __shared__ float kc[24 * 257];
    const int t = threadIdx.x;
    const int n0 = blockIdx.x * 256;
    const int h = blockIdx.y;
    const int b = blockIdx.z;
    const float* qb = qbuf + ((size_t)b * Cc + h * HDim) * Ntok + n0;
    const float* kb = kbuf + ((size_t)b * Cc + h * HDim) * Ntok + n0;
    for (int e = t; e < 24 * 256; e += 256) {
        int c = e >> 8, n = e & 255;
        qc[c * 257 + n] = qb[(size_t)c * Ntok + n];
        kc[c * 257 + n] = kb[(size_t)c * Ntok + n];
    }
    __syncthreads();
    float g0 = 0.f, g1 = 0.f, g2 = 0.f;
    const int c1 = t / 24, d1 = t % 24;
    const int e2 = t + 256; const int c2 = e2 / 24, d2 = e2 % 24;
    const int e3 = t + 512;
    const int c3 = (t < 64) ? e3 / 24 : 0, d3 = (t < 64) ? e3 % 24 : 0;
    for (int n = 0; n < 256; ++n) {
        g0 = fmaf(qc[c1 * 257 + n], kc[d1 * 257 + n], g0);
        g1 = fmaf(qc[c2 * 257 + n], kc[d2 * 257 + n], g1);
        g2 = fmaf(qc[c3 * 257 + n], kc[d3 * 257 + n], g2);
    }
    float* gp = gram + (size_t)(b * NHEADS + h) * 576;
    atomicAdd(gp + t, g0);
    atomicAdd(gp + e2, g1);
    if (t < 64) atomicAdd(gp + e3, g2);
    if (t < 24) {
        float s = 0.f;
        for (int n = 0; n < 256; ++n) { float v = qc[t * 257 + n]; s = fmaf(v, v, s); }
        atomicAdd(ssq_q + b * Cc + h * HDim + t, s);
    } else if (t < 48) {
        int d = t - 24; float s = 0.f;
        for (int n = 0; n < 256; ++n) { float v = kc[d * 257 + n]; s = fmaf(v, v, s); }
        atomicAdd(ssq_k + b * Cc + h * HDim + d, s);
    }
}

// K4: normalize gram -> softmax attn; pooled = attn @ vmean; channel-gate MLP.
__global__ __launch_bounds__(256) void k_attn(const float* __restrict__ gram,
                                              const float* __restrict__ ssq_q,
                                              const float* __restrict__ ssq_k,
                                              const float* __restrict__ temperature,
                                              const float* __restrict__ vmean,
                                              const float* __restrict__ ci_w1,
                                              const float* __restrict__ ci_b1,
                                              const float* __restrict__ bn2_g,
                                              const float* __restrict__ bn2_b,
                                              const float* __restrict__ bn2_m,
                                              const float* __restrict__ bn2_v,
                                              const float* __restrict__ ci_w2,
                                              const float* __restrict__ ci_b2,
                                              float* __restrict__ attn,
                                              float* __restrict__ sig_ch)
{
    __shared__ float pooled[192];
    __shared__ float cmv[24];
    const int b = blockIdx.x, t = threadIdx.x;
    if (t < 192) {
        int h = t / 24, c = t % 24;
        const float* gp = gram + (size_t)(b * NHEADS + h) * 576 + c * 24;
        float qn = fmaxf(sqrtf(ssq_q[b * Cc + h * HDim + c]), 1e-12f);
        float temp = temperature[h];
        float logit[24];
        float m = -1e30f;
#pragma unroll
        for (int d = 0; d < 24; ++d) {
            float kn = fmaxf(sqrtf(ssq_k[b * Cc + h * HDim + d]), 1e-12f);
            float l = gp[d] / (qn * kn) * temp;
            logit[d] = l; m = fmaxf(m, l);
        }
        float s = 0.f;
#pragma unroll
        for (int d = 0; d < 24; ++d) { float e = expf(logit[d] - m); logit[d] = e; s += e; }
        float inv = 1.f / s;
        float pool = 0.f;
        float* ap = attn + (size_t)(b * NHEADS + h) * 576 + c * 24;
#pragma unroll
        for (int d = 0; d < 24; ++d) {
            float a = logit[d] * inv;
            ap[d] = a;
            pool = fmaf(a, vmean[b * Cc + h * HDim + d], pool);
        }
        pooled[h * 24 + c] = pool * (1.0f / (float)Ntok);
    }
    __syncthreads();
    if (t < 24) {
        float z = ci_b1[t];
        for (int c = 0; c < 192; ++c) z = fmaf(ci_w1[t * 192 + c], pooled[c], z);
        float sc = bn2_g[t] / sqrtf(bn2_v[t] + EPSBN);
        z = z * sc + (bn2_b[t] - bn2_m[t] * sc);
        cmv[t] = gelu_f(z);
    }
    __syncthreads();
    if (t < 192) {
        float z = ci_b2[t];
#pragma unroll
        for (int o = 0; o < 24; ++o) z = fmaf(ci_w2[t * 24 + o], cmv[o], z);
        sig_ch[b * Cc + t] = sigmoid_f(z);
    }
}

// ---------------------------------------------------------------------------
// K4b: fold attention + gates into the projection: build per-batch
//   Pbig[384][192] = [ P_att = Abig^T @ proj ;  P_conv = diag(sig_ch)@proj ]
// stored TRANSPOSED as bf16 hi/lo planes: Pt[b][col j][k 0..383], hi then lo.
// grid (B, 9): part 0..7 = head h (P_att rows 24h..24h+23), part 8 = P_conv.
// ---------------------------------------------------------------------------
__global__ __launch_bounds__(192) void k_pprep(const float* __restrict__ attn,
                                               const float* __restrict__ sig_ch,
                                               const float* __restrict__ proj_w,
                                               __bf16* __restrict__ Pt)
{
    const int b = blockIdx.x, part = blockIdx.y, j = threadIdx.x;
    __bf16* base = Pt + (size_t)b * (2 * 73728);   // 73728 = 192*384
    if (part < 8) {
        const int h = part;
        __shared__ float at[576];
        for (int e = j; e < 576; e += 192) at[e] = attn[(size_t)(b * 8 + h) * 576 + e];
        __syncthreads();
        float pr[24];
#pragma unroll
        for (int cl = 0; cl < 24; ++cl) pr[cl] = proj_w[(h * 24 + cl) * 192 + j];
        float s[24];
#pragma unroll
        for (int d = 0; d < 24; ++d) s[d] = 0.f;
#pragma unroll
        for (int cl = 0; cl < 24; ++cl) {
            float a = pr[cl];
#pragma unroll
            for (int d = 0; d < 24; ++d) s[d] = fmaf(a, at[cl * 24 + d], s[d]);
        }
#pragma unroll
        for (int d = 0; d < 24; ++d) {
            float v = s[d];
            __bf16 hi = (__bf16)v;
            base[j * 384 + h * 24 + d] = hi;
            base[73728 + j * 384 + h * 24 + d] = (__bf16)(v - (float)hi);
        }
    } else {
        __shared__ float sch_s[192];
        sch_s[j] = sig_ch[b * Cc + j];
        __syncthreads();
        for (int ch = 0; ch < 192; ++ch) {
            float v = sch_s[ch] * proj_w[ch * 192 + j];
            __bf16 hi = (__bf16)v;
            base[j * 384 + 192 + ch] = hi;
            base[73728 + j * 384 + 192 + ch] = (__bf16)(v - (float)hi);
        }
    }
}

// K5: depthwise 3x3 conv + BN1 + GELU -> convx; fused spatial-gate MLP.
__global__ __launch_bounds__(256) void k_conv(const float* __restrict__ vbuf,
                                              const float* __restrict__ dw_w,
                                              const float* __restrict__ dw_b,
                                              const float* __restrict__ bn1_g,
                                              const float* __restrict__ bn1_b,
                                              const float* __restrict__ bn1_m,
                                              const float* __restrict__ bn1_v,
                                              const float* __restrict__ si_w1,
                                              const float* __restrict__ si_b1,
                                              const float* __restrict__ bn3_g,
                                              const float* __restrict__ bn3_b,
                                              const float* __restrict__ bn3_m,
                                              const float* __restrict__ bn3_v,
                                              const float* __restrict__ si_w2,
                                              const float* __restrict__ si_b2,
                                              float* __restrict__ convx,
                                              float* __restrict__ sig_sp)
{
    __shared__ float vh[16 * 324];     // 16ch x 18x18 halo
    __shared__ float sw1[12 * 192];
    __shared__ float dww[16 * 9];
    __shared__ float scl[16], shf[16];
    const int tx = threadIdx.x, ty = threadIdx.y;
    const int tid = ty * 16 + tx;
    const int x0 = blockIdx.x * 16, y0 = blockIdx.y * 16, b = blockIdx.z;
    for (int e = tid; e < 12 * 192; e += 256) sw1[e] = si_w1[e];
    float sm[12];
#pragma unroll
    for (int o = 0; o < 12; ++o) sm[o] = 0.f;
    const int gx = x0 + tx, gy = y0 + ty;
    for (int cc = 0; cc < 12; ++cc) {
        const int ch0 = cc * 16;
        __syncthreads();
        for (int e = tid; e < 16 * 324; e += 256) {
            int ch = e / 324, rem = e - ch * 324;
            int yy = rem / 18, xx = rem - yy * 18;
            int sy = y0 - 1 + yy, sx = x0 - 1 + xx;
            float v = 0.f;
            if (sy >= 0 && sy < Him && sx >= 0 && sx < Wim)
                v = vbuf[((size_t)b * Cc + ch0 + ch) * Ntok + sy * Wim + sx];
            vh[e] = v;
        }
        if (tid < 144) {
            dww[tid] = dw_w[ch0 * 9 + tid];
        } else if (tid < 160) {
            int ch = ch0 + tid - 144;
            float sc = bn1_g[ch] / sqrtf(bn1_v[ch] + EPSBN);
            scl[tid - 144] = sc;
            shf[tid - 144] = (dw_b[ch] - bn1_m[ch]) * sc + bn1_b[ch];
        }
        __syncthreads();
#pragma unroll 4
        for (int c = 0; c < 16; ++c) {
            const float* vp = vh + c * 324 + ty * 18 + tx;
            float conv =
                vp[0]  * dww[c * 9 + 0] + vp[1]  * dww[c * 9 + 1] + vp[2]  * dww[c * 9 + 2] +
                vp[18] * dww[c * 9 + 3] + vp[19] * dww[c * 9 + 4] + vp[20] * dww[c * 9 + 5] +
                vp[36] * dww[c * 9 + 6] + vp[37] * dww[c * 9 + 7] + vp[38] * dww[c * 9 + 8];
            float val = gelu_f(conv * scl[c] + shf[c]);
            convx[((size_t)b * Cc + ch0 + c) * Ntok + gy * Wim + gx] = val;
#pragma unroll
            for (int o = 0; o < 12; ++o) sm[o] = fmaf(sw1[o * 192 + ch0 + c], val, sm[o]);
        }
    }
    float sp = si_b2[0];
#pragma unroll
    for (int o = 0; o < 12; ++o) {
        float z = sm[o] + si_b1[o];
        float sc = bn3_g[o] / sqrtf(bn3_v[o] + EPSBN);
        z = z * sc + (bn3_b[o] - bn3_m[o] * sc);
        sp = fmaf(si_w2[o], gelu_f(z), sp);
    }
    sig_sp[b * Ntok + gy * Wim + gx] = sigmoid_f(sp);
}

// ---------------------------------------------------------------------------
// K6: fused epilogue GEMM via split-bf16 MFMA:
//   out[n][j] = [ sig_sp[n]*v^T | convx^T ] (128x384) @ Pt_b (384x192) + proj_b
// A staged per 32-K chunk from (C,N)-layout vbuf/convx (lane->token coalesced,
// 16 channels/thread -> b128 LDS writes); B is a pure LDS copy of the
// precomputed hi/lo planes. 3-split MFMA, 4 waves x (4x6) 16x16 tiles.
// ---------------------------------------------------------------------------
__global__ __launch_bounds__(256, 2) void k_final_mfma(const float* __restrict__ vbuf,
                                                       const float* __restrict__ convx,
                                                       const __bf16* __restrict__ Pt,
                                                       const float* __restrict__ sig_sp,
                                                       const float* __restrict__ proj_b,
                                                       float* __restrict__ out)
{
    __shared__ __align__(16) __bf16 Ah[128 * 40];
    __shared__ __align__(16) __bf16 Al[128 * 40];
    __shared__ __align__(16) __bf16 Bh[192 * 40];
    __shared__ __align__(16) __bf16 Bl[192 * 40];

    const int t = threadIdx.x;
    const int lane = t & 63, wave = t >> 6;
    const int n0 = blockIdx.x * 128;
    const int b = blockIdx.y;
    const int row_base = (wave & 1) * 64;
    const int col_base = (wave >> 1) * 96;
    const int m16 = lane & 15, q = lane >> 4;

    // A-staging map: thread -> (token an, 16-k half akh)
    const int an = t & 127;
    const int akh = (t >> 7) & 1;
    const float ssp_n = sig_sp[b * Ntok + n0 + an];
    const __bf16* ptb = Pt + (size_t)b * (2 * 73728);

    f32x4 acc[4][6];
#pragma unroll
    for (int rt = 0; rt < 4; ++rt)
#pragma unroll
        for (int ct = 0; ct < 6; ++ct)
#pragma unroll
            for (int j = 0; j < 4; ++j) acc[rt][ct][j] = 0.f;

    for (int kc = 0; kc < 12; ++kc) {
        // ---- stage A: 128 tokens x 32 k (k = channel index into [v | convx]) ----
        {
            const int ch0 = kc * 32 + akh * 16;
            const float* src;
            float scale;
            if (kc < 6) {
                src = vbuf + ((size_t)b * Cc + ch0) * Ntok + n0 + an;
                scale = ssp_n;
            } else {
                src = convx + ((size_t)b * Cc + (ch0 - 192)) * Ntok + n0 + an;
                scale = 1.f;
            }
            float xv[16];
#pragma unroll
            for (int jj = 0; jj < 16; ++jj)
                xv[jj] = src[(size_t)jj * Ntok] * scale;
            bf16x8 vh0, vl0, vh1, vl1;
            split8(xv, vh0, vl0);
            split8(xv + 8, vh1, vl1);
            const int o = an * 40 + akh * 16;
            *(bf16x8*)&Ah[o] = vh0; *(bf16x8*)&Ah[o + 8] = vh1;
            *(bf16x8*)&Al[o] = vl0; *(bf16x8*)&Al[o + 8] = vl1;
        }
        // ---- stage B: 192 cols x 32 k from pre-split planes ----
#pragma unroll
        for (int i = 0; i < 3; ++i) {
            int f = i * 256 + t;
            int col = f >> 2, k8 = (f & 3) << 3;
            const __bf16* sp = ptb + (size_t)col * 384 + kc * 32 + k8;
            bf16x8 vh = *(const bf16x8*)sp;
            bf16x8 vl = *(const bf16x8*)(sp + 73728);
            *(bf16x8*)&Bh[col * 40 + k8] = vh;
            *(bf16x8*)&Bl[col * 40 + k8] = vl;
        }
        __syncthreads();

        bf16x8 fah[4], fal[4], fbh[6], fbl[6];
#pragma unroll
        for (int rt = 0; rt < 4; ++rt) {
            int o = (row_base + rt * 16 + m16) * 40 + q * 8;
            fah[rt] = *(const bf16x8*)&Ah[o];
            fal[rt] = *(const bf16x8*)&Al[o];
        }
#pragma unroll
        for (int ct = 0; ct < 6; ++ct) {
            int o = (col_base + ct * 16 + m16) * 40 + q * 8;
            fbh[ct] = *(const bf16x8*)&Bh[o];
        }
        // hh + lh first (fbh live), then hl (fbl replaces fbh pressure)
#pragma unroll
        for (int rt = 0; rt < 4; ++rt)
#pragma unroll
            for (int ct = 0; ct < 6; ++ct) {
                acc[rt][ct] = __builtin_amdgcn_mfma_f32_16x16x32_bf16(
                    fah[rt], fbh[ct], acc[rt][ct], 0, 0, 0);
                acc[rt][ct] = __builtin_amdgcn_mfma_f32_16x16x32_bf16(
                    fal[rt], fbh[ct], acc[rt][ct], 0, 0, 0);
            }
#pragma unroll
        for (int ct = 0; ct < 6; ++ct) {
            int o = (col_base + ct * 16 + m16) * 40 + q * 8;
            fbl[ct] = *(const bf16x8*)&Bl[o];
        }
#pragma unroll
        for (int rt = 0; rt < 4; ++rt)
#pragma unroll
            for (int ct = 0; ct < 6; ++ct)
                acc[rt][ct] = __builtin_amdgcn_mfma_f32_16x16x32_bf16(
                    fah[rt], fbl[ct], acc[rt][ct], 0, 0, 0);
        __syncthreads();
    }

    // ---- epilogue: out (B,N,C) token-major + proj_b ----
    float* ob = out + ((size_t)b * Ntok + n0) * Cc;
#pragma unroll
    for (int ct = 0; ct < 6; ++ct) {
        const int col = col_base + ct * 16 + m16;
        const float pbv = proj_b[col];
#pragma unroll
        for (int rt = 0; rt < 4; ++rt) {
            const int row = row_base + rt * 16 + q * 4;
#pragma unroll
            for (int j = 0; j < 4; ++j)
                ob[(size_t)(row + j) * Cc + col] = acc[rt][ct][j] + pbv;
        }
    }
}

extern "C" void kernel_launch(void* const* d_in, const int* in_sizes, int n_in,
                              void* d_out, int out_size, void* d_ws, size_t ws_size,
                              hipStream_t stream)
{
    const float* x      = (const float*)d_in[0];
    const float* w_qkv  = (const float*)d_in[3];
    const float* temperature = (const float*)d_in[4];
    const float* dw_w   = (const float*)d_in[5];
    const float* dw_b   = (const float*)d_in[6];
    const float* bn1_g  = (const float*)d_in[7];
    const float* bn1_b  = (const float*)d_in[8];
    const float* bn1_m  = (const float*)d_in[9];
    const float* bn1_v  = (const float*)d_in[10];
    const float* ci_w1  = (const float*)d_in[11];
    const float* ci_b1  = (const float*)d_in[12];
    const float* bn2_g  = (const float*)d_in[13];
    const float* bn2_b  = (const float*)d_in[14];
    const float* bn2_m  = (const float*)d_in[15];
    const float* bn2_v  = (const float*)d_in[16];
    const float* ci_w2  = (const float*)d_in[17];
    const float* ci_b2  = (const float*)d_in[18];
    const float* si_w1  = (const float*)d_in[19];
    const float* si_b1  = (const float*)d_in[20];
    const float* bn3_g  = (const float*)d_in[21];
    const float* bn3_b  = (const float*)d_in[22];
    const float* bn3_m  = (const float*)d_in[23];
    const float* bn3_v  = (const float*)d_in[24];
    const float* si_w2  = (const float*)d_in[25];
    const float* si_b2  = (const float*)d_in[26];
    const float* proj_w = (const float*)d_in[27];
    const float* proj_b = (const float*)d_in[28];

    float* ws = (float*)d_ws;
    const size_t BCN = (size_t)Bb * Cc * Ntok;      // 25,165,824
    float* qbuf  = ws;
    float* kbuf  = ws + BCN;
    float* vbuf  = ws + 2 * BCN;
    float* gram  = ws + 3 * BCN;                    // 36864
    float* ssq_q = gram + 36864;                    // 1536
    float* ssq_k = ssq_q + 1536;                    // 1536
    float* vmean = ssq_k + 1536;                    // 1536 (holds channel SUMS)
    float* attn  = vmean + 1536;                    // 36864
    float* sig_ch = attn + 36864;                   // 1536
    float* sig_sp = sig_ch + 1536;                  // 131072
    float* convx = qbuf;       // q region dead after k_gram -> conv_x
    __bf16* Pt   = (__bf16*)kbuf;  // k region dead after k_gram -> Pbig planes
    float* out = (float*)d_out;

    // bf16 hi/lo transposed w_qkv in tail of d_out (dead until k_final's write)
    __bf16* wt = (__bf16*)(out + BCN - 110592);

    hipMemsetAsync(gram, 0, (36864 + 3 * 1536) * sizeof(float), stream);

    k_wprep<<<dim3(432), 256, 0, stream>>>(w_qkv, wt);
    k_qkv_mfma<<<dim3(Ntok / 128, Bb, 3), 256, 0, stream>>>(x, wt, ws, vmean);
    k_gram<<<dim3(Ntok / 256, NHEADS, Bb), 256, 0, stream>>>(qbuf, kbuf, gram, ssq_q, ssq_k);
    k_attn<<<dim3(Bb), 256, 0, stream>>>(gram, ssq_q, ssq_k, temperature, vmean,
                                         ci_w1, ci_b1, bn2_g, bn2_b, bn2_m, bn2_v,
                                         ci_w2, ci_b2, attn, sig_ch);
    k_pprep<<<dim3(Bb, 9), 192, 0, stream>>>(attn, sig_ch, proj_w, Pt);
    k_conv<<<dim3(Wim / 16, Him / 16, Bb), dim3(16, 16), 0, stream>>>(
        vbuf, dw_w, dw_b, bn1_g, bn1_b, bn1_m, bn1_v,
        si_w1, si_b1, bn3_g, bn3_b, bn3_m, bn3_v, si_w2, si_b2, convx, sig_sp);
    k_final_mfma<<<dim3(Ntok / 128, Bb), 256, 0, stream>>>(vbuf, convx, Pt, sig_sp,
                                                           proj_b, out);
}

// Round 5
// 686.345 us; speedup vs baseline: 1.8155x; 1.0724x over previous
//
#include <hip/hip_runtime.h>
#include <math.h>

// Problem constants (fixed by setup_inputs)
#define Bb 8
#define Cc 192
#define NHEADS 8
#define HDim 24
#define Him 128
#define Wim 128
#define Ntok 16384   // H*W
#define EPSBN 1e-5f

typedef __bf16 bf16x8 __attribute__((ext_vector_type(8)));
typedef float  f32x4  __attribute__((ext_vector_type(4)));

static __device__ __forceinline__ float gelu_f(float v) {
    return 0.5f * v * (1.0f + erff(v * 0.70710678118654752f));
}
static __device__ __forceinline__ float sigmoid_f(float v) {
    return 1.0f / (1.0f + expf(-v));
}
static __device__ __forceinline__ void split8(const float* xv, bf16x8& h8, bf16x8& l8) {
#pragma unroll
    for (int j = 0; j < 8; ++j) {
        float v = xv[j];
        __bf16 h = (__bf16)v;
        h8[j] = h;
        l8[j] = (__bf16)(v - (float)h);
    }
}

// ---------------------------------------------------------------------------
// K0: one-time prep: transpose w_qkv (192x576 fp32) into bf16 hi/lo planes in
// [col][k] layout. Stored in tail of d_out (dead until k_final's final write).
// ---------------------------------------------------------------------------
__global__ __launch_bounds__(256) void k_wprep(const float* __restrict__ w,
                                               __bf16* __restrict__ wt)
{
    int idx = blockIdx.x * 256 + threadIdx.x;   // 192*576 = 110592 total
    if (idx >= 192 * 576) return;
    int k = idx / 576, c = idx % 576;           // coalesced read over c
    float v = w[idx];
    __bf16 h = (__bf16)v;
    __bf16 l = (__bf16)(v - (float)h);
    wt[c * 192 + k] = h;
    wt[110592 + c * 192 + k] = l;
}

// ---------------------------------------------------------------------------
// K1: qkv projection via split-bf16 MFMA. Block = 128 tokens x 192 cols of
// section sec. Output transposed to (B,C,N). v-section blocks also
// accumulate per-channel sums (replaces k_vmean).
// ---------------------------------------------------------------------------
__global__ __launch_bounds__(256, 2) void k_qkv_mfma(const float* __restrict__ x,
                                                     const __bf16* __restrict__ wt,
                                                     float* __restrict__ qkv,
                                                     float* __restrict__ vsum)
{
    __shared__ __align__(16) __bf16 Ah[128 * 40];
    __shared__ __align__(16) __bf16 Al[128 * 40];
    __shared__ __align__(16) __bf16 Bh[192 * 40];
    __shared__ __align__(16) __bf16 Bl[192 * 40];

    const int t = threadIdx.x;
    const int lane = t & 63, wave = t >> 6;
    const int n0 = blockIdx.x * 128;
    const int b = blockIdx.y;
    const int sec = blockIdx.z;
    const int row_base = (wave & 1) * 64;
    const int col_base = (wave >> 1) * 96;
    const int m16 = lane & 15, q = lane >> 4;

    f32x4 acc[4][6];
#pragma unroll
    for (int rt = 0; rt < 4; ++rt)
#pragma unroll
        for (int ct = 0; ct < 6; ++ct)
#pragma unroll
            for (int j = 0; j < 4; ++j) acc[rt][ct][j] = 0.f;

    const int ar = t >> 1, ahalf = t & 1;
    const float* xrow = x + ((size_t)b * Ntok + n0 + ar) * Cc + ahalf * 16;

    for (int kc = 0; kc < 6; ++kc) {
        {
            const float4* xp4 = (const float4*)(xrow + kc * 32);
            float xv[16];
            float4 u;
            u = xp4[0]; xv[0] = u.x; xv[1] = u.y; xv[2]  = u.z; xv[3]  = u.w;
            u = xp4[1]; xv[4] = u.x; xv[5] = u.y; xv[6]  = u.z; xv[7]  = u.w;
            u = xp4[2]; xv[8] = u.x; xv[9] = u.y; xv[10] = u.z; xv[11] = u.w;
            u = xp4[3]; xv[12] = u.x; xv[13] = u.y; xv[14] = u.z; xv[15] = u.w;
            bf16x8 vh0, vh1, vl0, vl1;
            split8(xv, vh0, vl0);
            split8(xv + 8, vh1, vl1);
            const int o = ar * 40 + ahalf * 16;
            *(bf16x8*)&Ah[o] = vh0; *(bf16x8*)&Ah[o + 8] = vh1;
            *(bf16x8*)&Al[o] = vl0; *(bf16x8*)&Al[o + 8] = vl1;
        }
#pragma unroll
        for (int i = 0; i < 3; ++i) {
            int f = i * 256 + t;
            int n = f >> 2, k8 = (f & 3) << 3;
            const __bf16* src = wt + ((size_t)(sec * 192 + n)) * 192 + kc * 32 + k8;
            bf16x8 vh = *(const bf16x8*)src;
            bf16x8 vl = *(const bf16x8*)(src + 110592);
            *(bf16x8*)&Bh[n * 40 + k8] = vh;
            *(bf16x8*)&Bl[n * 40 + k8] = vl;
        }
        __syncthreads();

        bf16x8 fah[4], fal[4], fbh[6], fbl[6];
#pragma unroll
        for (int rt = 0; rt < 4; ++rt) {
            int o = (row_base + rt * 16 + m16) * 40 + q * 8;
            fah[rt] = *(const bf16x8*)&Ah[o];
            fal[rt] = *(const bf16x8*)&Al[o];
        }
#pragma unroll
        for (int ct = 0; ct < 6; ++ct) {
            int o = (col_base + ct * 16 + m16) * 40 + q * 8;
            fbh[ct] = *(const bf16x8*)&Bh[o];
            fbl[ct] = *(const bf16x8*)&Bl[o];
        }
#pragma unroll
        for (int rt = 0; rt < 4; ++rt)
#pragma unroll
            for (int ct = 0; ct < 6; ++ct) {
                acc[rt][ct] = __builtin_amdgcn_mfma_f32_16x16x32_bf16(
                    fah[rt], fbh[ct], acc[rt][ct], 0, 0, 0);
                acc[rt][ct] = __builtin_amdgcn_mfma_f32_16x16x32_bf16(
                    fah[rt], fbl[ct], acc[rt][ct], 0, 0, 0);
                acc[rt][ct] = __builtin_amdgcn_mfma_f32_16x16x32_bf16(
                    fal[rt], fbh[ct], acc[rt][ct], 0, 0, 0);
            }
        __syncthreads();
    }

    const size_t obase = (size_t)sec * ((size_t)Bb * Cc * Ntok)
                       + (size_t)b * Cc * (size_t)Ntok;
#pragma unroll
    for (int rt = 0; rt < 4; ++rt)
#pragma unroll
        for (int ct = 0; ct < 6; ++ct) {
            int token = n0 + row_base + rt * 16 + q * 4;
            int col = col_base + ct * 16 + m16;
            float4 o = make_float4(acc[rt][ct][0], acc[rt][ct][1],
                                   acc[rt][ct][2], acc[rt][ct][3]);
            *(float4*)(qkv + obase + (size_t)col * Ntok + token) = o;
        }

    if (sec == 2) {
#pragma unroll
        for (int ct = 0; ct < 6; ++ct) {
            float s = 0.f;
#pragma unroll
            for (int rt = 0; rt < 4; ++rt)
                s += acc[rt][ct][0] + acc[rt][ct][1] + acc[rt][ct][2] + acc[rt][ct][3];
            s += __shfl_xor(s, 16, 64);
            s += __shfl_xor(s, 32, 64);
            if (q == 0)
                atomicAdd(vsum + b * Cc + col_base + ct * 16 + m16, s);
        }
    }
}

// ---------------------------------------------------------------------------
// K2: Gram + sum-of-squares. grid (N/1024, HEADS, B): 4 sub-stages of 256
// tokens accumulate in registers, ONE atomicAdd at the end.
// ---------------------------------------------------------------------------
__global__ __launch_bounds__(256) void k_gram(const float* __restrict__ qbuf,
                                              const float* __restrict__ kbuf,
                                              float* __restrict__ gram,
                                              float* __restrict__ ssq_q,
                                              float* __restrict__ ssq_k)
{
    __shared__ float qc[24 * 257];
    __shared__ float kc[24 * 257];
    const int t = threadIdx.x;
    const int nb = blockIdx.x * 1024;
    const int h = blockIdx.y;
    const int b = blockIdx.z;
    const float* qb0 = qbuf + ((size_t)b * Cc + h * HDim) * Ntok + nb;
    const float* kb0 = kbuf + ((size_t)b * Cc + h * HDim) * Ntok + nb;

    float g0 = 0.f, g1 = 0.f, g2 = 0.f;
    float sq = 0.f, sk = 0.f;
    const int c1 = t / 24, d1 = t % 24;
    const int e2 = t + 256; const int c2 = e2 / 24, d2 = e2 % 24;
    const int e3 = t + 512;
    const int c3 = (t < 64) ? e3 / 24 : 0, d3 = (t < 64) ? e3 % 24 : 0;

    for (int st = 0; st < 4; ++st) {
        const float* qb = qb0 + st * 256;
        const float* kb = kb0 + st * 256;
        __syncthreads();
        for (int e = t; e < 24 * 256; e += 256) {
            int c = e >> 8, n = e & 255;
            qc[c * 257 + n] = qb[(size_t)c * Ntok + n];
            kc[c * 257 + n] = kb[(size_t)c * Ntok + n];
        }
        __syncthreads();
        for (int n = 0; n < 256; ++n) {
            g0 = fmaf(qc[c1 * 257 + n], kc[d1 * 257 + n], g0);
            g1 = fmaf(qc[c2 * 257 + n], kc[d2 * 257 + n], g1);
            g2 = fmaf(qc[c3 * 257 + n], kc[d3 * 257 + n], g2);
        }
        if (t < 24) {
            for (int n = 0; n < 256; ++n) { float v = qc[t * 257 + n]; sq = fmaf(v, v, sq); }
        } else if (t < 48) {
            int d = t - 24;
            for (int n = 0; n < 256; ++n) { float v = kc[d * 257 + n]; sk = fmaf(v, v, sk); }
        }
    }
    float* gp = gram + (size_t)(b * NHEADS + h) * 576;
    atomicAdd(gp + t, g0);
    atomicAdd(gp + e2, g1);
    if (t < 64) atomicAdd(gp + e3, g2);
    if (t < 24) atomicAdd(ssq_q + b * Cc + h * HDim + t, sq);
    else if (t < 48) atomicAdd(ssq_k + b * Cc + h * HDim + (t - 24), sk);
}

// K4: normalize gram -> softmax attn; pooled = attn @ vmean; channel-gate MLP.
__global__ __launch_bounds__(256) void k_attn(const float* __restrict__ gram,
                                              const float* __restrict__ ssq_q,
                                              const float* __restrict__ ssq_k,
                                              const float* __restrict__ temperature,
                                              const float* __restrict__ vmean,
                                              const float* __restrict__ ci_w1,
                                              const float* __restrict__ ci_b1,
                                              const float* __restrict__ bn2_g,
                                              const float* __restrict__ bn2_b,
                                              const float* __restrict__ bn2_m,
                                              const float* __restrict__ bn2_v,
                                              const float* __restrict__ ci_w2,
                                              const float* __restrict__ ci_b2,
                                              float* __restrict__ attn,
                                              float* __restrict__ sig_ch)
{
    __shared__ float pooled[192];
    __shared__ float cmv[24];
    const int b = blockIdx.x, t = threadIdx.x;
    if (t < 192) {
        int h = t / 24, c = t % 24;
        const float* gp = gram + (size_t)(b * NHEADS + h) * 576 + c * 24;
        float qn = fmaxf(sqrtf(ssq_q[b * Cc + h * HDim + c]), 1e-12f);
        float temp = temperature[h];
        float logit[24];
        float m = -1e30f;
#pragma unroll
        for (int d = 0; d < 24; ++d) {
            float kn = fmaxf(sqrtf(ssq_k[b * Cc + h * HDim + d]), 1e-12f);
            float l = gp[d] / (qn * kn) * temp;
            logit[d] = l; m = fmaxf(m, l);
        }
        float s = 0.f;
#pragma unroll
        for (int d = 0; d < 24; ++d) { float e = expf(logit[d] - m); logit[d] = e; s += e; }
        float inv = 1.f / s;
        float pool = 0.f;
        float* ap = attn + (size_t)(b * NHEADS + h) * 576 + c * 24;
#pragma unroll
        for (int d = 0; d < 24; ++d) {
            float a = logit[d] * inv;
            ap[d] = a;
            pool = fmaf(a, vmean[b * Cc + h * HDim + d], pool);
        }
        pooled[h * 24 + c] = pool * (1.0f / (float)Ntok);
    }
    __syncthreads();
    if (t < 24) {
        float z = ci_b1[t];
        for (int c = 0; c < 192; ++c) z = fmaf(ci_w1[t * 192 + c], pooled[c], z);
        float sc = bn2_g[t] / sqrtf(bn2_v[t] + EPSBN);
        z = z * sc + (bn2_b[t] - bn2_m[t] * sc);
        cmv[t] = gelu_f(z);
    }
    __syncthreads();
    if (t < 192) {
        float z = ci_b2[t];
#pragma unroll
        for (int o = 0; o < 24; ++o) z = fmaf(ci_w2[t * 24 + o], cmv[o], z);
        sig_ch[b * Cc + t] = sigmoid_f(z);
    }
}

// ---------------------------------------------------------------------------
// K4b: fold attention + channel gate into projection (see round 2 notes).
// ---------------------------------------------------------------------------
__global__ __launch_bounds__(192) void k_pprep(const float* __restrict__ attn,
                                               const float* __restrict__ sig_ch,
                                               const float* __restrict__ proj_w,
                                               __bf16* __restrict__ Pt)
{
    const int b = blockIdx.x, part = blockIdx.y, j = threadIdx.x;
    __bf16* base = Pt + (size_t)b * (2 * 73728);   // 73728 = 192*384
    if (part < 8) {
        const int h = part;
        __shared__ float at[576];
        for (int e = j; e < 576; e += 192) at[e] = attn[(size_t)(b * 8 + h) * 576 + e];
        __syncthreads();
        float pr[24];
#pragma unroll
        for (int cl = 0; cl < 24; ++cl) pr[cl] = proj_w[(h * 24 + cl) * 192 + j];
        float s[24];
#pragma unroll
        for (int d = 0; d < 24; ++d) s[d] = 0.f;
#pragma unroll
        for (int cl = 0; cl < 24; ++cl) {
            float a = pr[cl];
#pragma unroll
            for (int d = 0; d < 24; ++d) s[d] = fmaf(a, at[cl * 24 + d], s[d]);
        }
#pragma unroll
        for (int d = 0; d < 24; ++d) {
            float v = s[d];
            __bf16 hi = (__bf16)v;
            base[j * 384 + h * 24 + d] = hi;
            base[73728 + j * 384 + h * 24 + d] = (__bf16)(v - (float)hi);
        }
    } else {
        __shared__ float sch_s[192];
        sch_s[j] = sig_ch[b * Cc + j];
        __syncthreads();
        for (int ch = 0; ch < 192; ++ch) {
            float v = sch_s[ch] * proj_w[ch * 192 + j];
            __bf16 hi = (__bf16)v;
            base[j * 384 + 192 + ch] = hi;
            base[73728 + j * 384 + 192 + ch] = (__bf16)(v - (float)hi);
        }
    }
}

// ---------------------------------------------------------------------------
// K5 v2 (FIXED): depthwise 3x3 conv + BN1 + GELU. Block = 8 rows x 128 px x
// 8 ch; grid (16, 24, B) = 3072 blocks. BUG FIX from round 4: staging index
// decomposition used >>10 (1024) but per-channel extent is 10*128=1280 ->
// OOB LDS writes + uninit rows 8-9 -> NaN. Now /1280.
// ---------------------------------------------------------------------------
__global__ __launch_bounds__(256) void k_conv(const float* __restrict__ vbuf,
                                              const float* __restrict__ dw_w,
                                              const float* __restrict__ dw_b,
                                              const float* __restrict__ bn1_g,
                                              const float* __restrict__ bn1_b,
                                              const float* __restrict__ bn1_m,
                                              const float* __restrict__ bn1_v,
                                              float* __restrict__ convx)
{
    __shared__ float vh[8][10][130];   // 8 ch x 10 rows x (1 | 128 | 1) pad cols
    __shared__ float dww[8 * 9];
    __shared__ float scl[8], shf[8];
    const int t = threadIdx.x;
    const int y0 = blockIdx.x * 8;
    const int ch0 = blockIdx.y * 8;
    const int b = blockIdx.z;

    if (t < 72) {
        dww[t] = dw_w[ch0 * 9 + t];
    } else if (t < 80) {
        int c = t - 72, ch = ch0 + c;
        float sc = bn1_g[ch] / sqrtf(bn1_v[ch] + EPSBN);
        scl[c] = sc;
        shf[c] = (dw_b[ch] - bn1_m[ch]) * sc + bn1_b[ch];
    } else if (t < 160) {
        int e = t - 80;                 // zero the x-pad columns
        int ch = e / 10, r = e % 10;
        vh[ch][r][0] = 0.f;
        vh[ch][r][129] = 0.f;
    }
    // stage 8ch x 10 rows x 128 cols (rows y0-1 .. y0+8), coalesced full rows
    for (int e = t; e < 8 * 10 * 128; e += 256) {
        int ch = e / 1280, rem = e - ch * 1280;   // FIX: 1280, not 1024
        int r = rem >> 7, xc = rem & 127;
        int gy = y0 - 1 + r;
        float v = 0.f;
        if (gy >= 0 && gy < Him)
            v = vbuf[((size_t)b * Cc + ch0 + ch) * Ntok + gy * Wim + xc];
        vh[ch][r][xc + 1] = v;
    }
    __syncthreads();

    const int xc = t & 127, half = t >> 7;   // half: rows 0-3 / 4-7
#pragma unroll
    for (int ch = 0; ch < 8; ++ch) {
        const float w0 = dww[ch * 9 + 0], w1 = dww[ch * 9 + 1], w2 = dww[ch * 9 + 2];
        const float w3 = dww[ch * 9 + 3], w4 = dww[ch * 9 + 4], w5 = dww[ch * 9 + 5];
        const float w6 = dww[ch * 9 + 6], w7 = dww[ch * 9 + 7], w8 = dww[ch * 9 + 8];
        const float sc = scl[ch], sh = shf[ch];
        float* op = convx + ((size_t)b * Cc + ch0 + ch) * Ntok + (size_t)y0 * Wim + xc;
#pragma unroll
        for (int rr = 0; rr < 4; ++rr) {
            int r = half * 4 + rr;               // output row within tile
            const float* r0 = &vh[ch][r][xc];    // source rows r, r+1, r+2
            const float* r1 = &vh[ch][r + 1][xc];
            const float* r2 = &vh[ch][r + 2][xc];
            float conv = r0[0] * w0 + r0[1] * w1 + r0[2] * w2
                       + r1[0] * w3 + r1[1] * w4 + r1[2] * w5
                       + r2[0] * w6 + r2[1] * w7 + r2[2] * w8;
            op[(size_t)r * Wim] = gelu_f(conv * sc + sh);
        }
    }
}

// ---------------------------------------------------------------------------
// K6 v2: fused epilogue GEMM + spatial-gate MLP.
// Phase 0 (kc 6..11): A = convx chunks; MFMA vs P_conv AND vs si_w1^T (extra
//   16-col tile, lanes>=12 zero) -> first-layer sums in C-layout.
// Gate: dump to padded LDS, 128 threads do BN3+GELU+w2+sigmoid -> ssp_s.
// Phase 1 (kc 0..5): A = v chunks scaled by ssp_s[token]; MFMA vs P_att.
// ---------------------------------------------------------------------------
__global__ __launch_bounds__(256, 2) void k_final_mfma(const float* __restrict__ vbuf,
                                                       const float* __restrict__ convx,
                                                       const __bf16* __restrict__ Pt,
                                                       const float* __restrict__ si_w1,
                                                       const float* __restrict__ si_b1,
                                                       const float* __restrict__ bn3_g,
                                                       const float* __restrict__ bn3_b,
                                                       const float* __restrict__ bn3_m,
                                                       const float* __restrict__ bn3_v,
                                                       const float* __restrict__ si_w2,
                                                       const float* __restrict__ si_b2,
                                                       const float* __restrict__ proj_b,
                                                       float* __restrict__ out)
{
    __shared__ __align__(16) __bf16 Ah[128 * 40];
    __shared__ __align__(16) __bf16 Al[128 * 40];
    __shared__ __align__(16) __bf16 Bh[192 * 40];
    __shared__ __align__(16) __bf16 Bl[192 * 40];
    __shared__ float smbuf[128][17];
    __shared__ float ssp_s[128];

    const int t = threadIdx.x;
    const int lane = t & 63, wave = t >> 6;
    const int n0 = blockIdx.x * 128;
    const int b = blockIdx.y;
    const int row_base = (wave & 1) * 64;
    const int col_base = (wave >> 1) * 96;
    const int m16 = lane & 15, q = lane >> 4;

    const int an = t & 127;            // A-staging: token
    const int akh = (t >> 7) & 1;      // A-staging: 16-ch half
    const __bf16* ptb = Pt + (size_t)b * (2 * 73728);

    f32x4 acc[4][6];
#pragma unroll
    for (int rt = 0; rt < 4; ++rt)
#pragma unroll
        for (int ct = 0; ct < 6; ++ct)
#pragma unroll
            for (int j = 0; j < 4; ++j) acc[rt][ct][j] = 0.f;
    f32x4 accS[4];
#pragma unroll
    for (int rt = 0; rt < 4; ++rt)
#pragma unroll
        for (int j = 0; j < 4; ++j) accS[rt][j] = 0.f;

    for (int phase = 0; phase < 2; ++phase) {
        if (phase == 1) {
#pragma unroll
            for (int rt = 0; rt < 4; ++rt) {
                int row = row_base + rt * 16 + q * 4;
#pragma unroll
                for (int j = 0; j < 4; ++j)
                    smbuf[row + j][m16] = accS[rt][j];
            }
            __syncthreads();
            if (t < 128) {
                float sp = si_b2[0];
#pragma unroll
                for (int o = 0; o < 12; ++o) {
                    float z = smbuf[t][o] + si_b1[o];
                    float sc = bn3_g[o] / sqrtf(bn3_v[o] + EPSBN);
                    z = z * sc + (bn3_b[o] - bn3_m[o] * sc);
                    sp = fmaf(si_w2[o], gelu_f(z), sp);
                }
                ssp_s[t] = sigmoid_f(sp);
            }
            __syncthreads();
        }
        for (int ki = 0; ki < 6; ++ki) {
            const int kc = (phase == 0) ? (ki + 6) : ki;
            // ---- stage A ----
            {
                const int ch0 = ki * 32 + akh * 16;
                const float* src;
                float scale;
                if (phase == 0) {
                    src = convx + ((size_t)b * Cc + ch0) * Ntok + n0 + an;
                    scale = 1.f;
                } else {
                    src = vbuf + ((size_t)b * Cc + ch0) * Ntok + n0 + an;
                    scale = ssp_s[an];
                }
                float xv[16];
#pragma unroll
                for (int jj = 0; jj < 16; ++jj)
                    xv[jj] = src[(size_t)jj * Ntok] * scale;
                bf16x8 vh0, vl0, vh1, vl1;
                split8(xv, vh0, vl0);
                split8(xv + 8, vh1, vl1);
                const int o = an * 40 + akh * 16;
                *(bf16x8*)&Ah[o] = vh0; *(bf16x8*)&Ah[o + 8] = vh1;
                *(bf16x8*)&Al[o] = vl0; *(bf16x8*)&Al[o + 8] = vl1;
            }
            // ---- stage B from pre-split planes ----
#pragma unroll
            for (int i = 0; i < 3; ++i) {
                int f = i * 256 + t;
                int col = f >> 2, k8 = (f & 3) << 3;
                const __bf16* sp = ptb + (size_t)col * 384 + kc * 32 + k8;
                bf16x8 vh = *(const bf16x8*)sp;
                bf16x8 vl = *(const bf16x8*)(sp + 73728);
                *(bf16x8*)&Bh[col * 40 + k8] = vh;
                *(bf16x8*)&Bl[col * 40 + k8] = vl;
            }
            __syncthreads();

            bf16x8 fah[4], fal[4], fbh[6], fbl[6];
#pragma unroll
            for (int rt = 0; rt < 4; ++rt) {
                int o = (row_base + rt * 16 + m16) * 40 + q * 8;
                fah[rt] = *(const bf16x8*)&Ah[o];
                fal[rt] = *(const bf16x8*)&Al[o];
            }
#pragma unroll
            for (int ct = 0; ct < 6; ++ct) {
                int o = (col_base + ct * 16 + m16) * 40 + q * 8;
                fbh[ct] = *(const bf16x8*)&Bh[o];
            }
#pragma unroll
            for (int rt = 0; rt < 4; ++rt)
#pragma unroll
                for (int ct = 0; ct < 6; ++ct) {
                    acc[rt][ct] = __builtin_amdgcn_mfma_f32_16x16x32_bf16(
                        fah[rt], fbh[ct], acc[rt][ct], 0, 0, 0);
                    acc[rt][ct] = __builtin_amdgcn_mfma_f32_16x16x32_bf16(
                        fal[rt], fbh[ct], acc[rt][ct], 0, 0, 0);
                }
#pragma unroll
            for (int ct = 0; ct < 6; ++ct) {
                int o = (col_base + ct * 16 + m16) * 40 + q * 8;
                fbl[ct] = *(const bf16x8*)&Bl[o];
            }
#pragma unroll
            for (int rt = 0; rt < 4; ++rt)
#pragma unroll
                for (int ct = 0; ct < 6; ++ct)
                    acc[rt][ct] = __builtin_amdgcn_mfma_f32_16x16x32_bf16(
                        fah[rt], fbl[ct], acc[rt][ct], 0, 0, 0);

            if (phase == 0) {
                bf16x8 w1h, w1l;
                if (m16 < 12) {
                    const float* wp = si_w1 + m16 * 192 + ki * 32 + q * 8;
                    float wv[8];
                    float4 u0 = *(const float4*)wp, u1 = *(const float4*)(wp + 4);
                    wv[0] = u0.x; wv[1] = u0.y; wv[2] = u0.z; wv[3] = u0.w;
                    wv[4] = u1.x; wv[5] = u1.y; wv[6] = u1.z; wv[7] = u1.w;
                    split8(wv, w1h, w1l);
                } else {
#pragma unroll
                    for (int j = 0; j < 8; ++j) { w1h[j] = (__bf16)0.f; w1l[j] = (__bf16)0.f; }
                }
#pragma unroll
                for (int rt = 0; rt < 4; ++rt) {
                    accS[rt] = __builtin_amdgcn_mfma_f32_16x16x32_bf16(
                        fah[rt], w1h, accS[rt], 0, 0, 0);
                    accS[rt] = __builtin_amdgcn_mfma_f32_16x16x32_bf16(
                        fal[rt], w1h, accS[rt], 0, 0, 0);
                    accS[rt] = __builtin_amdgcn_mfma_f32_16x16x32_bf16(
                        fah[rt], w1l, accS[rt], 0, 0, 0);
                }
            }
            __syncthreads();
        }
    }

    // ---- epilogue: out (B,N,C) token-major + proj_b ----
    float* ob = out + ((size_t)b * Ntok + n0) * Cc;
#pragma unroll
    for (int ct = 0; ct < 6; ++ct) {
        const int col = col_base + ct * 16 + m16;
        const float pbv = proj_b[col];
#pragma unroll
        for (int rt = 0; rt < 4; ++rt) {
            const int row = row_base + rt * 16 + q * 4;
#pragma unroll
            for (int j = 0; j < 4; ++j)
                ob[(size_t)(row + j) * Cc + col] = acc[rt][ct][j] + pbv;
        }
    }
}

extern "C" void kernel_launch(void* const* d_in, const int* in_sizes, int n_in,
                              void* d_out, int out_size, void* d_ws, size_t ws_size,
                              hipStream_t stream)
{
    const float* x      = (const float*)d_in[0];
    const float* w_qkv  = (const float*)d_in[3];
    const float* temperature = (const float*)d_in[4];
    const float* dw_w   = (const float*)d_in[5];
    const float* dw_b   = (const float*)d_in[6];
    const float* bn1_g  = (const float*)d_in[7];
    const float* bn1_b  = (const float*)d_in[8];
    const float* bn1_m  = (const float*)d_in[9];
    const float* bn1_v  = (const float*)d_in[10];
    const float* ci_w1  = (const float*)d_in[11];
    const float* ci_b1  = (const float*)d_in[12];
    const float* bn2_g  = (const float*)d_in[13];
    const float* bn2_b  = (const float*)d_in[14];
    const float* bn2_m  = (const float*)d_in[15];
    const float* bn2_v  = (const float*)d_in[16];
    const float* ci_w2  = (const float*)d_in[17];
    const float* ci_b2  = (const float*)d_in[18];
    const float* si_w1  = (const float*)d_in[19];
    const float* si_b1  = (const float*)d_in[20];
    const float* bn3_g  = (const float*)d_in[21];
    const float* bn3_b  = (const float*)d_in[22];
    const float* bn3_m  = (const float*)d_in[23];
    const float* bn3_v  = (const float*)d_in[24];
    const float* si_w2  = (const float*)d_in[25];
    const float* si_b2  = (const float*)d_in[26];
    const float* proj_w = (const float*)d_in[27];
    const float* proj_b = (const float*)d_in[28];

    float* ws = (float*)d_ws;
    const size_t BCN = (size_t)Bb * Cc * Ntok;      // 25,165,824
    float* qbuf  = ws;
    float* kbuf  = ws + BCN;
    float* vbuf  = ws + 2 * BCN;
    float* gram  = ws + 3 * BCN;                    // 36864
    float* ssq_q = gram + 36864;                    // 1536
    float* ssq_k = ssq_q + 1536;                    // 1536
    float* vmean = ssq_k + 1536;                    // 1536 (holds channel SUMS)
    float* attn  = vmean + 1536;                    // 36864
    float* sig_ch = attn + 36864;                   // 1536
    float* convx = qbuf;       // q region dead after k_gram -> conv_x
    __bf16* Pt   = (__bf16*)kbuf;  // k region dead after k_gram -> Pbig planes
    float* out = (float*)d_out;

    __bf16* wt = (__bf16*)(out + BCN - 110592);

    hipMemsetAsync(gram, 0, (36864 + 3 * 1536) * sizeof(float), stream);

    k_wprep<<<dim3(432), 256, 0, stream>>>(w_qkv, wt);
    k_qkv_mfma<<<dim3(Ntok / 128, Bb, 3), 256, 0, stream>>>(x, wt, ws, vmean);
    k_gram<<<dim3(Ntok / 1024, NHEADS, Bb), 256, 0, stream>>>(qbuf, kbuf, gram, ssq_q, ssq_k);
    k_attn<<<dim3(Bb), 256, 0, stream>>>(gram, ssq_q, ssq_k, temperature, vmean,
                                         ci_w1, ci_b1, bn2_g, bn2_b, bn2_m, bn2_v,
                                         ci_w2, ci_b2, attn, sig_ch);
    k_pprep<<<dim3(Bb, 9), 192, 0, stream>>>(attn, sig_ch, proj_w, Pt);
    k_conv<<<dim3(Him / 8, Cc / 8, Bb), 256, 0, stream>>>(
        vbuf, dw_w, dw_b, bn1_g, bn1_b, bn1_m, bn1_v, convx);
    k_final_mfma<<<dim3(Ntok / 128, Bb), 256, 0, stream>>>(
        vbuf, convx, Pt, si_w1, si_b1, bn3_g, bn3_b, bn3_m, bn3_v,
        si_w2, si_b2, proj_b, out);
}